// Round 1
// baseline (684.506 us; speedup 1.0000x reference)
//
#include <hip/hip_runtime.h>
#include <hip/hip_bf16.h>
#include <math.h>

// HarmonicCausalSelfAttention: B=4 T=2048 C=1024 H=16 R=64 D=64, alpha=0.7
// Pipeline:
//   tq/tk/tv = (x @ V_p^T) * s          [8192,64] f32   (k_gemm_xv)
//   q,k      = t @ U^T  -> bf16 [B,H,T,D]               (k_gemm_tu MODE 0)
//   v        = t @ U^T  -> bf16 [B,H,D,T] (transposed)  (k_gemm_tu MODE 1)
//   y        = causal flash attention -> bf16 [B,T,C]   (k_attn)
//   ty       = (y @ cV^T) * s                           (k_gemm_xv)
//   out      = ty @ cU^T -> f32 [B,T,C]                 (k_gemm_tu MODE 2)
// v/c projections use split-bf16 (3-term MFMA) for accuracy.

#define NB 4
#define NT 2048
#define NC 1024
#define NH 16
#define NR 64
#define ND 64
#define NM (NB * NT)  // 8192

typedef __attribute__((ext_vector_type(8))) short short8;
typedef __attribute__((ext_vector_type(4))) float f32x4;
typedef __attribute__((ext_vector_type(4))) float float4v;

__device__ __forceinline__ short f2bf(float f) {
    union { __hip_bfloat16 h; short s; } u;
    u.h = __float2bfloat16(f);
    return u.s;
}
__device__ __forceinline__ float bf2f(short s) {
    union { short s; __hip_bfloat16 h; } u;
    u.s = s;
    return __bfloat162float(u.h);
}
__device__ __forceinline__ f32x4 MFMA(short8 a, short8 b, f32x4 c) {
    return __builtin_amdgcn_mfma_f32_16x16x32_bf16(a, b, c, 0, 0, 0);
}
__device__ __forceinline__ short8 ld8_hi(const float* __restrict__ p) {
    float4v a = *(const float4v*)p;
    float4v b = *(const float4v*)(p + 4);
    short8 r;
    r[0] = f2bf(a[0]); r[1] = f2bf(a[1]); r[2] = f2bf(a[2]); r[3] = f2bf(a[3]);
    r[4] = f2bf(b[0]); r[5] = f2bf(b[1]); r[6] = f2bf(b[2]); r[7] = f2bf(b[3]);
    return r;
}
__device__ __forceinline__ void ld8_split(const float* __restrict__ p, short8& hi, short8& lo) {
    float4v a = *(const float4v*)p;
    float4v b = *(const float4v*)(p + 4);
    float v[8] = {a[0], a[1], a[2], a[3], b[0], b[1], b[2], b[3]};
#pragma unroll
    for (int j = 0; j < 8; j++) {
        short h = f2bf(v[j]);
        hi[j] = h;
        lo[j] = f2bf(v[j] - bf2f(h));
    }
}

// ---- stage 1: T[m,r] = (X[m,:] . Vm[r,:]) * s_r ;  X is f32 (TIN_BF=0) or bf16 (TIN_BF=1)
template <int TIN_BF, int SPLIT>
__global__ __launch_bounds__(256) void k_gemm_xv(const void* __restrict__ Xv,
                                                 const float* __restrict__ Vm,
                                                 float* __restrict__ Tm) {
    const int w = threadIdx.x >> 6, l = threadIdx.x & 63;
    const int lr = l & 15, lk = l >> 4;
    const size_t m = (size_t)blockIdx.x * 64 + w * 16 + lr;

    f32x4 acc[4];
#pragma unroll
    for (int nt = 0; nt < 4; nt++) acc[nt] = 0.0f;

    for (int k0 = 0; k0 < NC; k0 += 32) {
        short8 ah = (short)0, al = (short)0;
        if constexpr (TIN_BF) {
            ah = *(const short8*)((const short*)Xv + m * NC + k0 + lk * 8);
        } else if constexpr (SPLIT) {
            ld8_split((const float*)Xv + m * NC + k0 + lk * 8, ah, al);
        } else {
            ah = ld8_hi((const float*)Xv + m * NC + k0 + lk * 8);
        }
#pragma unroll
        for (int nt = 0; nt < 4; nt++) {
            const float* vp = Vm + (size_t)(nt * 16 + lr) * NC + k0 + lk * 8;
            if constexpr (SPLIT) {
                short8 bh, bl;
                ld8_split(vp, bh, bl);
                acc[nt] = MFMA(ah, bh, acc[nt]);
                acc[nt] = MFMA(ah, bl, acc[nt]);
                if constexpr (!TIN_BF) acc[nt] = MFMA(al, bh, acc[nt]);
            } else {
                acc[nt] = MFMA(ah, ld8_hi(vp), acc[nt]);
            }
        }
    }
    const int mo = blockIdx.x * 64 + w * 16 + lk * 4;
#pragma unroll
    for (int nt = 0; nt < 4; nt++) {
        const int r = nt * 16 + lr;
        const float sc = powf((float)(r + 1), -0.7f);
#pragma unroll
        for (int i = 0; i < 4; i++)
            Tm[(size_t)(mo + i) * NR + r] = acc[nt][i] * sc;
    }
}

// ---- stage 2: P[m,n] = T[m,:] . Um[n,:]   (K = 64)
// MODE 0: bf16 out at [B,H,T,D]; MODE 1: bf16 out at [B,H,D,T]; MODE 2: f32 out [M,C]
template <int MODE, int SPLIT>
__global__ __launch_bounds__(256) void k_gemm_tu(const float* __restrict__ Tm,
                                                 const float* __restrict__ Um,
                                                 void* __restrict__ Outp) {
    const int w = threadIdx.x >> 6, l = threadIdx.x & 63;
    const int lr = l & 15, lk = l >> 4;
    const size_t m = (size_t)blockIdx.x * 64 + w * 16 + lr;
    const int n0 = blockIdx.y * 256;

    short8 ah[2], al[2];
#pragma unroll
    for (int ks = 0; ks < 2; ks++) {
        if constexpr (SPLIT)
            ld8_split(Tm + m * NR + ks * 32 + lk * 8, ah[ks], al[ks]);
        else
            ah[ks] = ld8_hi(Tm + m * NR + ks * 32 + lk * 8);
    }
    f32x4 acc[16];
#pragma unroll
    for (int nt = 0; nt < 16; nt++) acc[nt] = 0.0f;
#pragma unroll
    for (int ks = 0; ks < 2; ks++) {
#pragma unroll
        for (int nt = 0; nt < 16; nt++) {
            const float* up = Um + (size_t)(n0 + nt * 16 + lr) * NR + ks * 32 + lk * 8;
            if constexpr (SPLIT) {
                short8 bh, bl;
                ld8_split(up, bh, bl);
                acc[nt] = MFMA(ah[ks], bh, acc[nt]);
                acc[nt] = MFMA(ah[ks], bl, acc[nt]);
                acc[nt] = MFMA(al[ks], bh, acc[nt]);
            } else {
                acc[nt] = MFMA(ah[ks], ld8_hi(up), acc[nt]);
            }
        }
    }
    const int mo = blockIdx.x * 64 + w * 16 + lk * 4;
#pragma unroll
    for (int nt = 0; nt < 16; nt++) {
        const int n = n0 + nt * 16 + lr;
#pragma unroll
        for (int i = 0; i < 4; i++) {
            const int mm = mo + i;
            if constexpr (MODE == 2) {
                ((float*)Outp)[(size_t)mm * NC + n] = acc[nt][i];
            } else {
                const int bb = mm >> 11, tt = mm & (NT - 1);
                const int hh = n >> 6, dd = n & 63;
                const size_t idx = (MODE == 0)
                                       ? (((size_t)(bb * NH + hh) * NT + tt) * ND + dd)
                                       : (((size_t)(bb * NH + hh) * ND + dd) * NT + tt);
                ((short*)Outp)[idx] = f2bf(acc[nt][i]);
            }
        }
    }
}

// ---- causal flash attention. grid (T/64, B*H), 4 waves/block, 16 q-rows/wave.
// Q,K: [B,H,T,D] bf16. Vt: [B,H,D,T] bf16. Y: [B,T,C] bf16.
__global__ __launch_bounds__(256) void k_attn(const short* __restrict__ Qm,
                                              const short* __restrict__ Km,
                                              const short* __restrict__ Vt,
                                              short* __restrict__ Y) {
    __shared__ __align__(16) short Plds[4][16][72];  // per-wave P tile, padded (2-way bank alias = free)
    const int w = threadIdx.x >> 6, l = threadIdx.x & 63;
    const int lr = l & 15, lk = l >> 4;
    const int bh = blockIdx.y;
    const int q0 = blockIdx.x * 64 + w * 16;  // this wave's first q row

    const short* Qp = Qm + ((size_t)bh * NT + q0) * ND;
    short8 qf[2];
#pragma unroll
    for (int ks = 0; ks < 2; ks++)
        qf[ks] = *(const short8*)(Qp + (size_t)lr * ND + ks * 32 + lk * 8);

    float m_r[4], l_r[4];
    f32x4 o[4];
#pragma unroll
    for (int i = 0; i < 4; i++) { m_r[i] = -1e30f; l_r[i] = 0.0f; }
#pragma unroll
    for (int dt = 0; dt < 4; dt++) o[dt] = 0.0f;

    const short* Kb = Km + (size_t)bh * NT * ND;
    const short* Vb = Vt + (size_t)bh * ND * NT;
    const int ntile = ((q0 + 15) >> 6) + 1;  // causal: kv tiles 0..floor((q0+15)/64)

    for (int it = 0; it < ntile; ++it) {
        const int kv0 = it * 64;
        f32x4 sa[4];
#pragma unroll
        for (int nt = 0; nt < 4; nt++) sa[nt] = 0.0f;
#pragma unroll
        for (int ks = 0; ks < 2; ks++) {
#pragma unroll
            for (int nt = 0; nt < 4; nt++) {
                const short8 kf =
                    *(const short8*)(Kb + (size_t)(kv0 + nt * 16 + lr) * ND + ks * 32 + lk * 8);
                sa[nt] = MFMA(qf[ks], kf, sa[nt]);
            }
        }
        // scale + causal mask; D layout: row = lk*4+i, col = lr (per 16x16 tile nt)
        float sv[4][4];
#pragma unroll
        for (int nt = 0; nt < 4; nt++) {
            const int kv = kv0 + nt * 16 + lr;
#pragma unroll
            for (int i = 0; i < 4; i++) {
                const float s = sa[nt][i] * 0.125f;
                sv[nt][i] = (kv <= q0 + lk * 4 + i) ? s : -1e30f;
            }
        }
        // online softmax: row reductions across the 16 lanes sharing lk
        float rmax[4];
#pragma unroll
        for (int i = 0; i < 4; i++)
            rmax[i] = fmaxf(fmaxf(sv[0][i], sv[1][i]), fmaxf(sv[2][i], sv[3][i]));
#pragma unroll
        for (int d = 1; d < 16; d <<= 1) {
#pragma unroll
            for (int i = 0; i < 4; i++) rmax[i] = fmaxf(rmax[i], __shfl_xor(rmax[i], d));
        }
        float fac[4];
#pragma unroll
        for (int i = 0; i < 4; i++) {
            const float mn = fmaxf(m_r[i], rmax[i]);
            fac[i] = __expf(m_r[i] - mn);
            m_r[i] = mn;
        }
        float rsum[4];
#pragma unroll
        for (int i = 0; i < 4; i++) rsum[i] = 0.0f;
#pragma unroll
        for (int nt = 0; nt < 4; nt++) {
#pragma unroll
            for (int i = 0; i < 4; i++) {
                const float p = __expf(sv[nt][i] - m_r[i]);
                sv[nt][i] = p;
                rsum[i] += p;
            }
        }
#pragma unroll
        for (int d = 1; d < 16; d <<= 1) {
#pragma unroll
            for (int i = 0; i < 4; i++) rsum[i] += __shfl_xor(rsum[i], d);
        }
#pragma unroll
        for (int i = 0; i < 4; i++) l_r[i] = l_r[i] * fac[i] + rsum[i];
#pragma unroll
        for (int dt = 0; dt < 4; dt++) {
#pragma unroll
            for (int i = 0; i < 4; i++) o[dt][i] *= fac[i];
        }
        // transpose P through per-wave LDS (acc layout -> A-frag layout)
#pragma unroll
        for (int nt = 0; nt < 4; nt++) {
#pragma unroll
            for (int i = 0; i < 4; i++)
                Plds[w][lk * 4 + i][nt * 16 + lr] = f2bf(sv[nt][i]);
        }
        // PV: A = P (from LDS), B = V^T rows (contiguous along kv)
#pragma unroll
        for (int ks = 0; ks < 2; ks++) {
            const short8 pa = *(const short8*)&Plds[w][lr][ks * 32 + lk * 8];
#pragma unroll
            for (int dt = 0; dt < 4; dt++) {
                const short8 vf =
                    *(const short8*)(Vb + (size_t)(dt * 16 + lr) * NT + kv0 + ks * 32 + lk * 8);
                o[dt] = MFMA(pa, vf, o[dt]);
            }
        }
    }
    const int b = bh >> 4, h = bh & 15;
#pragma unroll
    for (int i = 0; i < 4; i++) {
        const float inv = 1.0f / l_r[i];
        const int t = q0 + lk * 4 + i;
        short* yp = Y + ((size_t)b * NT + t) * NC + h * ND;
#pragma unroll
        for (int dt = 0; dt < 4; dt++) yp[dt * 16 + lr] = f2bf(o[dt][i] * inv);
    }
}

extern "C" void kernel_launch(void* const* d_in, const int* in_sizes, int n_in,
                              void* d_out, int out_size, void* d_ws, size_t ws_size,
                              hipStream_t stream) {
    const float* x = (const float*)d_in[0];
    const float* qU = (const float*)d_in[1];
    const float* qV = (const float*)d_in[2];
    const float* kU = (const float*)d_in[3];
    const float* kV = (const float*)d_in[4];
    const float* vU = (const float*)d_in[5];
    const float* vV = (const float*)d_in[6];
    const float* cU = (const float*)d_in[7];
    const float* cV = (const float*)d_in[8];
    float* out = (float*)d_out;

    char* ws = (char*)d_ws;
    size_t off = 0;
    auto take = [&](size_t bytes) {
        char* p = ws + off;
        off += (bytes + 255) & ~(size_t)255;
        return p;
    };
    float* tq = (float*)take((size_t)NM * NR * 4);
    float* tk = (float*)take((size_t)NM * NR * 4);
    float* tv = (float*)take((size_t)NM * NR * 4);
    float* ty = (float*)take((size_t)NM * NR * 4);
    short* qb = (short*)take((size_t)NM * NC * 2);
    short* kb = (short*)take((size_t)NM * NC * 2);
    short* vtb = (short*)take((size_t)NM * NC * 2);
    short* yb = (short*)take((size_t)NM * NC * 2);

    dim3 blk(256);
    dim3 g1(NM / 64);
    dim3 g2(NM / 64, NC / 256);

    k_gemm_xv<0, 0><<<g1, blk, 0, stream>>>(x, qV, tq);
    k_gemm_xv<0, 0><<<g1, blk, 0, stream>>>(x, kV, tk);
    k_gemm_xv<0, 1><<<g1, blk, 0, stream>>>(x, vV, tv);
    k_gemm_tu<0, 0><<<g2, blk, 0, stream>>>(tq, qU, qb);
    k_gemm_tu<0, 0><<<g2, blk, 0, stream>>>(tk, kU, kb);
    k_gemm_tu<1, 1><<<g2, blk, 0, stream>>>(tv, vU, vtb);
    k_attn<<<dim3(NT / 64, NB * NH), blk, 0, stream>>>(qb, kb, vtb, yb);
    k_gemm_xv<1, 1><<<g1, blk, 0, stream>>>(yb, cV, ty);
    k_gemm_tu<2, 1><<<g2, blk, 0, stream>>>(ty, cU, out);
}

// Round 2
// 447.800 us; speedup vs baseline: 1.5286x; 1.5286x over previous
//
#include <hip/hip_runtime.h>
#include <hip/hip_bf16.h>
#include <math.h>

// HarmonicCausalSelfAttention: B=4 T=2048 C=1024 H=16 R=64 D=64, alpha=0.7
// Pipeline:
//   tq/tk/tv = (x @ V_p^T) * s          [8192,64] f32   (k_gemm_xv)
//   q,k      = t @ U^T  -> bf16 [B,H,T,D]               (k_gemm_tu MODE 0)
//   v        = t @ U^T  -> bf16 [B,H,D,T] (transposed)  (k_gemm_tu MODE 1)
//   y        = causal flash attention -> bf16 [B,T,C]   (k_attn)
//   ty       = (y @ cV^T) * s                           (k_gemm_xv)
//   out      = ty @ cU^T -> f32 [B,T,C]                 (k_gemm_tu MODE 2)
// v/c projections use split-bf16 (3-term MFMA) for accuracy.
//
// R1: k_attn restructured — block-level K/V LDS staging (XOR-swizzled, both
// sides), reg-staged prefetch of next tile during compute, and causal work
// pairing (block j handles q-tiles at 32j and 2016-32j -> equal work/block).

#define NB 4
#define NT 2048
#define NC 1024
#define NH 16
#define NR 64
#define ND 64
#define NM (NB * NT)  // 8192

typedef __attribute__((ext_vector_type(8))) short short8;
typedef __attribute__((ext_vector_type(4))) float f32x4;
typedef __attribute__((ext_vector_type(4))) float float4v;
typedef __attribute__((ext_vector_type(4))) int int4v;

__device__ __forceinline__ short f2bf(float f) {
    union { __hip_bfloat16 h; short s; } u;
    u.h = __float2bfloat16(f);
    return u.s;
}
__device__ __forceinline__ float bf2f(short s) {
    union { short s; __hip_bfloat16 h; } u;
    u.s = s;
    return __bfloat162float(u.h);
}
__device__ __forceinline__ f32x4 MFMA(short8 a, short8 b, f32x4 c) {
    return __builtin_amdgcn_mfma_f32_16x16x32_bf16(a, b, c, 0, 0, 0);
}
__device__ __forceinline__ short8 ld8_hi(const float* __restrict__ p) {
    float4v a = *(const float4v*)p;
    float4v b = *(const float4v*)(p + 4);
    short8 r;
    r[0] = f2bf(a[0]); r[1] = f2bf(a[1]); r[2] = f2bf(a[2]); r[3] = f2bf(a[3]);
    r[4] = f2bf(b[0]); r[5] = f2bf(b[1]); r[6] = f2bf(b[2]); r[7] = f2bf(b[3]);
    return r;
}
__device__ __forceinline__ void ld8_split(const float* __restrict__ p, short8& hi, short8& lo) {
    float4v a = *(const float4v*)p;
    float4v b = *(const float4v*)(p + 4);
    float v[8] = {a[0], a[1], a[2], a[3], b[0], b[1], b[2], b[3]};
#pragma unroll
    for (int j = 0; j < 8; j++) {
        short h = f2bf(v[j]);
        hi[j] = h;
        lo[j] = f2bf(v[j] - bf2f(h));
    }
}

// ---- stage 1: T[m,r] = (X[m,:] . Vm[r,:]) * s_r ;  X is f32 (TIN_BF=0) or bf16 (TIN_BF=1)
template <int TIN_BF, int SPLIT>
__global__ __launch_bounds__(256) void k_gemm_xv(const void* __restrict__ Xv,
                                                 const float* __restrict__ Vm,
                                                 float* __restrict__ Tm) {
    const int w = threadIdx.x >> 6, l = threadIdx.x & 63;
    const int lr = l & 15, lk = l >> 4;
    const size_t m = (size_t)blockIdx.x * 64 + w * 16 + lr;

    f32x4 acc[4];
#pragma unroll
    for (int nt = 0; nt < 4; nt++) acc[nt] = 0.0f;

    for (int k0 = 0; k0 < NC; k0 += 32) {
        short8 ah = (short)0, al = (short)0;
        if constexpr (TIN_BF) {
            ah = *(const short8*)((const short*)Xv + m * NC + k0 + lk * 8);
        } else if constexpr (SPLIT) {
            ld8_split((const float*)Xv + m * NC + k0 + lk * 8, ah, al);
        } else {
            ah = ld8_hi((const float*)Xv + m * NC + k0 + lk * 8);
        }
#pragma unroll
        for (int nt = 0; nt < 4; nt++) {
            const float* vp = Vm + (size_t)(nt * 16 + lr) * NC + k0 + lk * 8;
            if constexpr (SPLIT) {
                short8 bh, bl;
                ld8_split(vp, bh, bl);
                acc[nt] = MFMA(ah, bh, acc[nt]);
                acc[nt] = MFMA(ah, bl, acc[nt]);
                if constexpr (!TIN_BF) acc[nt] = MFMA(al, bh, acc[nt]);
            } else {
                acc[nt] = MFMA(ah, ld8_hi(vp), acc[nt]);
            }
        }
    }
    const int mo = blockIdx.x * 64 + w * 16 + lk * 4;
#pragma unroll
    for (int nt = 0; nt < 4; nt++) {
        const int r = nt * 16 + lr;
        const float sc = powf((float)(r + 1), -0.7f);
#pragma unroll
        for (int i = 0; i < 4; i++)
            Tm[(size_t)(mo + i) * NR + r] = acc[nt][i] * sc;
    }
}

// ---- stage 2: P[m,n] = T[m,:] . Um[n,:]   (K = 64)
// MODE 0: bf16 out at [B,H,T,D]; MODE 1: bf16 out at [B,H,D,T]; MODE 2: f32 out [M,C]
template <int MODE, int SPLIT>
__global__ __launch_bounds__(256) void k_gemm_tu(const float* __restrict__ Tm,
                                                 const float* __restrict__ Um,
                                                 void* __restrict__ Outp) {
    const int w = threadIdx.x >> 6, l = threadIdx.x & 63;
    const int lr = l & 15, lk = l >> 4;
    const size_t m = (size_t)blockIdx.x * 64 + w * 16 + lr;
    const int n0 = blockIdx.y * 256;

    short8 ah[2], al[2];
#pragma unroll
    for (int ks = 0; ks < 2; ks++) {
        if constexpr (SPLIT)
            ld8_split(Tm + m * NR + ks * 32 + lk * 8, ah[ks], al[ks]);
        else
            ah[ks] = ld8_hi(Tm + m * NR + ks * 32 + lk * 8);
    }
    f32x4 acc[16];
#pragma unroll
    for (int nt = 0; nt < 16; nt++) acc[nt] = 0.0f;
#pragma unroll
    for (int ks = 0; ks < 2; ks++) {
#pragma unroll
        for (int nt = 0; nt < 16; nt++) {
            const float* up = Um + (size_t)(n0 + nt * 16 + lr) * NR + ks * 32 + lk * 8;
            if constexpr (SPLIT) {
                short8 bh, bl;
                ld8_split(up, bh, bl);
                acc[nt] = MFMA(ah[ks], bh, acc[nt]);
                acc[nt] = MFMA(ah[ks], bl, acc[nt]);
                acc[nt] = MFMA(al[ks], bh, acc[nt]);
            } else {
                acc[nt] = MFMA(ah[ks], ld8_hi(up), acc[nt]);
            }
        }
    }
    const int mo = blockIdx.x * 64 + w * 16 + lk * 4;
#pragma unroll
    for (int nt = 0; nt < 16; nt++) {
        const int n = n0 + nt * 16 + lr;
#pragma unroll
        for (int i = 0; i < 4; i++) {
            const int mm = mo + i;
            if constexpr (MODE == 2) {
                ((float*)Outp)[(size_t)mm * NC + n] = acc[nt][i];
            } else {
                const int bb = mm >> 11, tt = mm & (NT - 1);
                const int hh = n >> 6, dd = n & 63;
                const size_t idx = (MODE == 0)
                                       ? (((size_t)(bb * NH + hh) * NT + tt) * ND + dd)
                                       : (((size_t)(bb * NH + hh) * ND + dd) * NT + tt);
                ((short*)Outp)[idx] = f2bf(acc[nt][i]);
            }
        }
    }
}

// swizzled LDS fragment read: tile is [64 rows][64 cols] bf16, row stride 128B,
// byte offset XORed with (row&7)<<4 (write side uses the same XOR).
__device__ __forceinline__ short8 lds_frag(const short* base, int row, int cb) {
    return *(const short8*)((const char*)base + (((row << 7) + cb) ^ ((row & 7) << 4)));
}

// ---- causal flash attention. grid (32, B*H), 4 waves/block.
// Block j: waves 0,1 -> q rows [32j, 32j+32); waves 2,3 -> [2016-32j, 2048-32j).
// Q,K: [B,H,T,D] bf16. Vt: [B,H,D,T] bf16. Y: [B,T,C] bf16.
__global__ __launch_bounds__(256) void k_attn(const short* __restrict__ Qm,
                                              const short* __restrict__ Km,
                                              const short* __restrict__ Vt,
                                              short* __restrict__ Y) {
    __shared__ __align__(16) short Kl[64 * 64];      // 8 KB, swizzled
    __shared__ __align__(16) short Vl[64 * 64];      // 8 KB, swizzled
    __shared__ __align__(16) short Plds[4][16][72];  // per-wave P tile, padded
    const int tid = threadIdx.x;
    const int w = tid >> 6, l = tid & 63;
    const int lr = l & 15, lk = l >> 4;
    const int bh = blockIdx.y;
    const int qA0 = blockIdx.x * 32;
    const int qB0 = (NT - 32) - blockIdx.x * 32;
    const int q0 = (w < 2 ? qA0 : qB0) + (w & 1) * 16;  // this wave's first q row
    const int mymax = (q0 + 15) >> 6;                   // last causal kv tile for this wave
    const int ntile = ((qB0 + 31) >> 6) + 1;            // tiles staged by the block

    const short* Qp = Qm + ((size_t)bh * NT + q0) * ND;
    short8 qf[2];
#pragma unroll
    for (int ks = 0; ks < 2; ks++)
        qf[ks] = *(const short8*)(Qp + (size_t)lr * ND + ks * 32 + lk * 8);

    const short* Kb = Km + (size_t)bh * NT * ND;
    const short* Vb = Vt + (size_t)bh * ND * NT;

    // staging: 256 threads x 16B x 2 chunks per matrix (8 KB each)
    const int srow = tid >> 3;        // 0..31 (chunk row, +32 for second chunk)
    const int scol = (tid & 7) * 8;   // short offset within row
    const int loff0 = ((srow << 7) + (scol << 1)) ^ ((srow & 7) << 4);
    const int loff1 = (((srow + 32) << 7) + (scol << 1)) ^ ((srow & 7) << 4);

    float m_r[4], l_r[4];
    f32x4 o[4];
#pragma unroll
    for (int i = 0; i < 4; i++) { m_r[i] = -1e30f; l_r[i] = 0.0f; }
#pragma unroll
    for (int dt = 0; dt < 4; dt++) o[dt] = 0.0f;

    // prologue: issue tile-0 loads into registers
    int4v k0r = *(const int4v*)(Kb + (size_t)srow * ND + scol);
    int4v k1r = *(const int4v*)(Kb + (size_t)(srow + 32) * ND + scol);
    int4v v0r = *(const int4v*)(Vb + (size_t)srow * NT + scol);
    int4v v1r = *(const int4v*)(Vb + (size_t)(srow + 32) * NT + scol);

    for (int it = 0; it < ntile; ++it) {
        __syncthreads();  // previous tile's LDS reads complete
        *(int4v*)((char*)Kl + loff0) = k0r;
        *(int4v*)((char*)Kl + loff1) = k1r;
        *(int4v*)((char*)Vl + loff0) = v0r;
        *(int4v*)((char*)Vl + loff1) = v1r;
        __syncthreads();
        if (it + 1 < ntile) {  // prefetch next tile; lands during compute below
            const int kv0n = (it + 1) * 64;
            k0r = *(const int4v*)(Kb + (size_t)(kv0n + srow) * ND + scol);
            k1r = *(const int4v*)(Kb + (size_t)(kv0n + srow + 32) * ND + scol);
            v0r = *(const int4v*)(Vb + (size_t)srow * NT + kv0n + scol);
            v1r = *(const int4v*)(Vb + (size_t)(srow + 32) * NT + kv0n + scol);
        }
        if (it > mymax) continue;  // past causal range: stage only
        const int kv0 = it * 64;

        f32x4 sa[4];
#pragma unroll
        for (int nt = 0; nt < 4; nt++) sa[nt] = 0.0f;
#pragma unroll
        for (int ks = 0; ks < 2; ks++) {
#pragma unroll
            for (int nt = 0; nt < 4; nt++) {
                const short8 kf = lds_frag(Kl, nt * 16 + lr, ks * 64 + lk * 16);
                sa[nt] = MFMA(qf[ks], kf, sa[nt]);
            }
        }
        // scale + causal mask; D layout: row = lk*4+i, col = lr (per 16x16 tile nt)
        float sv[4][4];
#pragma unroll
        for (int nt = 0; nt < 4; nt++) {
            const int kv = kv0 + nt * 16 + lr;
#pragma unroll
            for (int i = 0; i < 4; i++) {
                const float s = sa[nt][i] * 0.125f;
                sv[nt][i] = (kv <= q0 + lk * 4 + i) ? s : -1e30f;
            }
        }
        // online softmax: row reductions across the 16 lanes sharing lk
        float rmax[4];
#pragma unroll
        for (int i = 0; i < 4; i++)
            rmax[i] = fmaxf(fmaxf(sv[0][i], sv[1][i]), fmaxf(sv[2][i], sv[3][i]));
#pragma unroll
        for (int d = 1; d < 16; d <<= 1) {
#pragma unroll
            for (int i = 0; i < 4; i++) rmax[i] = fmaxf(rmax[i], __shfl_xor(rmax[i], d));
        }
        float fac[4];
#pragma unroll
        for (int i = 0; i < 4; i++) {
            const float mn = fmaxf(m_r[i], rmax[i]);
            fac[i] = __expf(m_r[i] - mn);
            m_r[i] = mn;
        }
        float rsum[4];
#pragma unroll
        for (int i = 0; i < 4; i++) rsum[i] = 0.0f;
#pragma unroll
        for (int nt = 0; nt < 4; nt++) {
#pragma unroll
            for (int i = 0; i < 4; i++) {
                const float p = __expf(sv[nt][i] - m_r[i]);
                sv[nt][i] = p;
                rsum[i] += p;
            }
        }
#pragma unroll
        for (int d = 1; d < 16; d <<= 1) {
#pragma unroll
            for (int i = 0; i < 4; i++) rsum[i] += __shfl_xor(rsum[i], d);
        }
#pragma unroll
        for (int i = 0; i < 4; i++) l_r[i] = l_r[i] * fac[i] + rsum[i];
#pragma unroll
        for (int dt = 0; dt < 4; dt++) {
#pragma unroll
            for (int i = 0; i < 4; i++) o[dt][i] *= fac[i];
        }
        // transpose P through per-wave LDS (acc layout -> A-frag layout)
#pragma unroll
        for (int nt = 0; nt < 4; nt++) {
#pragma unroll
            for (int i = 0; i < 4; i++)
                Plds[w][lk * 4 + i][nt * 16 + lr] = f2bf(sv[nt][i]);
        }
        // PV: A = P (from LDS), B = V^T rows (kv-contiguous, from swizzled LDS)
#pragma unroll
        for (int ks = 0; ks < 2; ks++) {
            const short8 pa = *(const short8*)&Plds[w][lr][ks * 32 + lk * 8];
#pragma unroll
            for (int dt = 0; dt < 4; dt++) {
                const short8 vf = lds_frag(Vl, dt * 16 + lr, ks * 64 + lk * 16);
                o[dt] = MFMA(pa, vf, o[dt]);
            }
        }
    }
    const int b = bh >> 4, h = bh & 15;
#pragma unroll
    for (int i = 0; i < 4; i++) {
        const float inv = 1.0f / l_r[i];
        const int t = q0 + lk * 4 + i;
        short* yp = Y + ((size_t)b * NT + t) * NC + h * ND;
#pragma unroll
        for (int dt = 0; dt < 4; dt++) yp[dt * 16 + lr] = f2bf(o[dt][i] * inv);
    }
}

extern "C" void kernel_launch(void* const* d_in, const int* in_sizes, int n_in,
                              void* d_out, int out_size, void* d_ws, size_t ws_size,
                              hipStream_t stream) {
    const float* x = (const float*)d_in[0];
    const float* qU = (const float*)d_in[1];
    const float* qV = (const float*)d_in[2];
    const float* kU = (const float*)d_in[3];
    const float* kV = (const float*)d_in[4];
    const float* vU = (const float*)d_in[5];
    const float* vV = (const float*)d_in[6];
    const float* cU = (const float*)d_in[7];
    const float* cV = (const float*)d_in[8];
    float* out = (float*)d_out;

    char* ws = (char*)d_ws;
    size_t off = 0;
    auto take = [&](size_t bytes) {
        char* p = ws + off;
        off += (bytes + 255) & ~(size_t)255;
        return p;
    };
    float* tq = (float*)take((size_t)NM * NR * 4);
    float* tk = (float*)take((size_t)NM * NR * 4);
    float* tv = (float*)take((size_t)NM * NR * 4);
    float* ty = (float*)take((size_t)NM * NR * 4);
    short* qb = (short*)take((size_t)NM * NC * 2);
    short* kb = (short*)take((size_t)NM * NC * 2);
    short* vtb = (short*)take((size_t)NM * NC * 2);
    short* yb = (short*)take((size_t)NM * NC * 2);

    dim3 blk(256);
    dim3 g1(NM / 64);
    dim3 g2(NM / 64, NC / 256);

    k_gemm_xv<0, 0><<<g1, blk, 0, stream>>>(x, qV, tq);
    k_gemm_xv<0, 0><<<g1, blk, 0, stream>>>(x, kV, tk);
    k_gemm_xv<0, 1><<<g1, blk, 0, stream>>>(x, vV, tv);
    k_gemm_tu<0, 0><<<g2, blk, 0, stream>>>(tq, qU, qb);
    k_gemm_tu<0, 0><<<g2, blk, 0, stream>>>(tk, kU, kb);
    k_gemm_tu<1, 1><<<g2, blk, 0, stream>>>(tv, vU, vtb);
    k_attn<<<dim3(32, NB * NH), blk, 0, stream>>>(qb, kb, vtb, yb);
    k_gemm_xv<1, 1><<<g1, blk, 0, stream>>>(yb, cV, ty);
    k_gemm_tu<2, 1><<<g2, blk, 0, stream>>>(ty, cU, out);
}

// Round 4
// 245.254 us; speedup vs baseline: 2.7910x; 1.8259x over previous
//
#include <hip/hip_runtime.h>
#include <hip/hip_bf16.h>
#include <math.h>

// HarmonicCausalSelfAttention: B=4 T=2048 C=1024 H=16 R=64 D=64, alpha=0.7
// R3 = R2 with the PV fragment-read addressing bug fixed (pb1 col 32, not 64).
//   k_prep : split 8 weight mats to bf16 hi/lo, fold s_r into V-mats, 0.125 into qU
//   k_xv3  : fused tq|tk|tv = x @ Vs^T  -> Thi3 [8192][192] bf16 (+Tlov for v part)
//   k_tu   : q,k (1-term), v (3-term, transposed out), c-out (3-term f32)
//   k_attn : causal flash attn, swapped-operand MFMA -> per-lane scalar softmax
//   k_yv   : ty = y @ cVs^T (2-term) -> tyhi/tylo

#define NB 4
#define NT 2048
#define NC 1024
#define NH 16
#define NR 64
#define ND 64
#define NM (NB * NT)  // 8192

typedef __attribute__((ext_vector_type(8))) short short8;
typedef __attribute__((ext_vector_type(4))) short short4v;
typedef __attribute__((ext_vector_type(4))) float f32x4;
typedef __attribute__((ext_vector_type(4))) float float4v;
typedef __attribute__((ext_vector_type(4))) int int4v;

__device__ __forceinline__ short f2bf(float f) {
    union { __hip_bfloat16 h; short s; } u;
    u.h = __float2bfloat16(f);
    return u.s;
}
__device__ __forceinline__ float bf2f(short s) {
    union { short s; __hip_bfloat16 h; } u;
    u.s = s;
    return __bfloat162float(u.h);
}
__device__ __forceinline__ f32x4 MFMA(short8 a, short8 b, f32x4 c) {
    return __builtin_amdgcn_mfma_f32_16x16x32_bf16(a, b, c, 0, 0, 0);
}
__device__ __forceinline__ void ld8_split(const float* __restrict__ p, short8& hi, short8& lo) {
    float4v a = *(const float4v*)p;
    float4v b = *(const float4v*)(p + 4);
    float v[8] = {a[0], a[1], a[2], a[3], b[0], b[1], b[2], b[3]};
#pragma unroll
    for (int j = 0; j < 8; j++) {
        short h = f2bf(v[j]);
        hi[j] = h;
        lo[j] = f2bf(v[j] - bf2f(h));
    }
}

// ---- weight prep: mats 0-3 = qV,kV,vV,cV ([64][1024], scaled by s_row);
//      mats 4-7 = qU,kU,vU,cU ([1024][64]; qU additionally x0.125)
__global__ __launch_bounds__(256) void k_prep(const float* __restrict__ qV, const float* __restrict__ kV,
                                              const float* __restrict__ vV, const float* __restrict__ cV,
                                              const float* __restrict__ qU, const float* __restrict__ kU,
                                              const float* __restrict__ vU, const float* __restrict__ cU,
                                              short* __restrict__ Whi, short* __restrict__ Wlo) {
    const int mat = blockIdx.y;
    const int idx = blockIdx.x * 256 + threadIdx.x;
    const float* src;
    switch (mat) {
        case 0: src = qV; break;
        case 1: src = kV; break;
        case 2: src = vV; break;
        case 3: src = cV; break;
        case 4: src = qU; break;
        case 5: src = kU; break;
        case 6: src = vU; break;
        default: src = cU; break;
    }
    float sc = 1.0f;
    if (mat < 4) sc = powf((float)((idx >> 10) + 1), -0.7f);
    if (mat == 4) sc = 0.125f;
    const float v = src[idx] * sc;
    const short h = f2bf(v);
    Whi[mat * 65536 + idx] = h;
    Wlo[mat * 65536 + idx] = f2bf(v - bf2f(h));
}

// ---- fused stage 1: Thi3[m][p*64+r] for p in {q,k,v}; v also writes lo part.
__global__ __launch_bounds__(128) void k_xv3(const float* __restrict__ X,
                                             const short* __restrict__ Whi, const short* __restrict__ Wlo,
                                             short* __restrict__ Thi3, short* __restrict__ Tlov) {
    const int w = threadIdx.x >> 6, l = threadIdx.x & 63;
    const int lr = l & 15, lk = l >> 4;
    const size_t m = (size_t)blockIdx.x * 32 + w * 16 + lr;
    const short* qVh = Whi;
    const short* kVh = Whi + 65536;
    const short* vVh = Whi + 2 * 65536;
    const short* vVl = Wlo + 2 * 65536;

    f32x4 acc[12];
#pragma unroll
    for (int j = 0; j < 12; j++) acc[j] = 0.0f;

    for (int k0 = 0; k0 < NC; k0 += 32) {
        short8 xh, xl;
        ld8_split(X + m * NC + k0 + lk * 8, xh, xl);
        const int bo = k0 + lk * 8;
#pragma unroll
        for (int nt = 0; nt < 4; nt++) {
            const short8 bq = *(const short8*)(qVh + (size_t)(nt * 16 + lr) * NC + bo);
            acc[nt] = MFMA(xh, bq, acc[nt]);
        }
#pragma unroll
        for (int nt = 0; nt < 4; nt++) {
            const short8 bk = *(const short8*)(kVh + (size_t)(nt * 16 + lr) * NC + bo);
            acc[4 + nt] = MFMA(xh, bk, acc[4 + nt]);
        }
#pragma unroll
        for (int nt = 0; nt < 4; nt++) {
            const short8 bvh = *(const short8*)(vVh + (size_t)(nt * 16 + lr) * NC + bo);
            const short8 bvl = *(const short8*)(vVl + (size_t)(nt * 16 + lr) * NC + bo);
            acc[8 + nt] = MFMA(xh, bvh, acc[8 + nt]);
            acc[8 + nt] = MFMA(xh, bvl, acc[8 + nt]);
            acc[8 + nt] = MFMA(xl, bvh, acc[8 + nt]);
        }
    }
    const int mo = blockIdx.x * 32 + w * 16 + lk * 4;
#pragma unroll
    for (int p = 0; p < 3; p++) {
#pragma unroll
        for (int nt = 0; nt < 4; nt++) {
            const int col = p * 64 + nt * 16 + lr;
#pragma unroll
            for (int i = 0; i < 4; i++) {
                const float f = acc[p * 4 + nt][i];
                const short h = f2bf(f);
                Thi3[(size_t)(mo + i) * 192 + col] = h;
                if (p == 2) Tlov[(size_t)(mo + i) * 64 + nt * 16 + lr] = f2bf(f - bf2f(h));
            }
        }
    }
}

// ---- stage 2: P[m,n] = T[m,:] . U[n,:]  (K=64), pre-split bf16 inputs.
// MODE 0: bf16 [B,H,T,D]; MODE 1: bf16 [B,H,D,T]; MODE 2: f32 [M,C]
template <int TERMS, int MODE, int RSH, int COFF, int RSL>
__global__ __launch_bounds__(256) void k_tu(const short* __restrict__ Thi, const short* __restrict__ Tlo,
                                            const short* __restrict__ Uhi, const short* __restrict__ Ulo,
                                            void* __restrict__ Outp) {
    const int w = threadIdx.x >> 6, l = threadIdx.x & 63;
    const int lr = l & 15, lk = l >> 4;
    const size_t m = (size_t)blockIdx.x * 64 + w * 16 + lr;
    const int n0 = blockIdx.y * 256;

    short8 ah[2], al[2];
#pragma unroll
    for (int ks = 0; ks < 2; ks++) {
        ah[ks] = *(const short8*)(Thi + m * RSH + COFF + ks * 32 + lk * 8);
        if constexpr (TERMS == 3) al[ks] = *(const short8*)(Tlo + m * RSL + ks * 32 + lk * 8);
    }
    f32x4 acc[16];
#pragma unroll
    for (int nt = 0; nt < 16; nt++) acc[nt] = 0.0f;
#pragma unroll
    for (int ks = 0; ks < 2; ks++) {
#pragma unroll
        for (int nt = 0; nt < 16; nt++) {
            const size_t uo = (size_t)(n0 + nt * 16 + lr) * NR + ks * 32 + lk * 8;
            const short8 bh = *(const short8*)(Uhi + uo);
            acc[nt] = MFMA(ah[ks], bh, acc[nt]);
            if constexpr (TERMS == 3) {
                const short8 bl = *(const short8*)(Ulo + uo);
                acc[nt] = MFMA(ah[ks], bl, acc[nt]);
                acc[nt] = MFMA(al[ks], bh, acc[nt]);
            }
        }
    }
    const int mo = blockIdx.x * 64 + w * 16 + lk * 4;
#pragma unroll
    for (int nt = 0; nt < 16; nt++) {
        const int n = n0 + nt * 16 + lr;
#pragma unroll
        for (int i = 0; i < 4; i++) {
            const int mm = mo + i;
            if constexpr (MODE == 2) {
                ((float*)Outp)[(size_t)mm * NC + n] = acc[nt][i];
            } else {
                const int bb = mm >> 11, tt = mm & (NT - 1);
                const int hh = n >> 6, dd = n & 63;
                const size_t idx = (MODE == 0)
                                       ? (((size_t)(bb * NH + hh) * NT + tt) * ND + dd)
                                       : (((size_t)(bb * NH + hh) * ND + dd) * NT + tt);
                ((short*)Outp)[idx] = f2bf(acc[nt][i]);
            }
        }
    }
}

// ---- c-path stage 1: ty = y @ cVs^T, 2-term (y bf16 x split cVs)
__global__ __launch_bounds__(128) void k_yv(const short* __restrict__ Yb,
                                            const short* __restrict__ Whi, const short* __restrict__ Wlo,
                                            short* __restrict__ tyhi, short* __restrict__ tylo) {
    const int w = threadIdx.x >> 6, l = threadIdx.x & 63;
    const int lr = l & 15, lk = l >> 4;
    const size_t m = (size_t)blockIdx.x * 32 + w * 16 + lr;
    const short* cVh = Whi + 3 * 65536;
    const short* cVl = Wlo + 3 * 65536;

    f32x4 acc[4];
#pragma unroll
    for (int nt = 0; nt < 4; nt++) acc[nt] = 0.0f;

    for (int k0 = 0; k0 < NC; k0 += 32) {
        const short8 ah = *(const short8*)(Yb + m * NC + k0 + lk * 8);
        const int bo = k0 + lk * 8;
#pragma unroll
        for (int nt = 0; nt < 4; nt++) {
            const short8 bh = *(const short8*)(cVh + (size_t)(nt * 16 + lr) * NC + bo);
            const short8 bl = *(const short8*)(cVl + (size_t)(nt * 16 + lr) * NC + bo);
            acc[nt] = MFMA(ah, bh, acc[nt]);
            acc[nt] = MFMA(ah, bl, acc[nt]);
        }
    }
    const int mo = blockIdx.x * 32 + w * 16 + lk * 4;
#pragma unroll
    for (int nt = 0; nt < 4; nt++) {
        const int col = nt * 16 + lr;
#pragma unroll
        for (int i = 0; i < 4; i++) {
            const float f = acc[nt][i];
            const short h = f2bf(f);
            tyhi[(size_t)(mo + i) * 64 + col] = h;
            tylo[(size_t)(mo + i) * 64 + col] = f2bf(f - bf2f(h));
        }
    }
}

// swizzled LDS fragment read: tile [64][64] bf16, row stride 128B, byte ^ (row&7)<<4
__device__ __forceinline__ short8 lds_frag(const short* base, int row, int cb) {
    return *(const short8*)((const char*)base + (((row << 7) + cb) ^ ((row & 7) << 4)));
}

// ---- causal flash attention, swapped operands. grid (32, B*H), 4 waves/block.
// Block j: waves 0,1 -> q rows [32j,32j+32); waves 2,3 -> [2016-32j, 2048-32j).
// Q,K: [B,H,T,D] bf16 (Q pre-scaled by 0.125). Vt: [B,H,D,T] bf16. Y: [B,T,C] bf16.
__global__ __launch_bounds__(256) void k_attn(const short* __restrict__ Qm,
                                              const short* __restrict__ Km,
                                              const short* __restrict__ Vt,
                                              short* __restrict__ Y) {
    __shared__ __align__(16) short Kl[64 * 64];   // 8 KB, swizzled
    __shared__ __align__(16) short Vl[64 * 64];   // 8 KB, swizzled
    __shared__ __align__(16) short Pl[4 * 1024];  // per-wave 16x64 P tile, swizzled
    const int tid = threadIdx.x;
    const int w = tid >> 6, l = tid & 63;
    const int lr = l & 15, lk = l >> 4;
    const int bh = blockIdx.y;
    const int qA0 = blockIdx.x * 32;
    const int qB0 = (NT - 32) - blockIdx.x * 32;
    const int q0 = (w < 2 ? qA0 : qB0) + (w & 1) * 16;
    const int mymax = (q0 + 15) >> 6;
    const int ntile = ((qB0 + 31) >> 6) + 1;

    const short* Qp = Qm + ((size_t)bh * NT + q0) * ND;
    short8 qf[2];
#pragma unroll
    for (int ks = 0; ks < 2; ks++)
        qf[ks] = *(const short8*)(Qp + (size_t)lr * ND + ks * 32 + lk * 8);

    const short* Kb = Km + (size_t)bh * NT * ND;
    const short* Vb = Vt + (size_t)bh * ND * NT;

    const int srow = tid >> 3;
    const int scol = (tid & 7) * 8;
    const int loff0 = ((srow << 7) + (scol << 1)) ^ ((srow & 7) << 4);
    const int loff1 = (((srow + 32) << 7) + (scol << 1)) ^ ((srow & 7) << 4);

    float m_s = -1e30f, l_s = 0.0f;
    f32x4 o[4];
#pragma unroll
    for (int dt = 0; dt < 4; dt++) o[dt] = 0.0f;

    char* plb = (char*)Pl + w * 2048;

    int4v k0r = *(const int4v*)(Kb + (size_t)srow * ND + scol);
    int4v k1r = *(const int4v*)(Kb + (size_t)(srow + 32) * ND + scol);
    int4v v0r = *(const int4v*)(Vb + (size_t)srow * NT + scol);
    int4v v1r = *(const int4v*)(Vb + (size_t)(srow + 32) * NT + scol);

    for (int it = 0; it < ntile; ++it) {
        __syncthreads();
        *(int4v*)((char*)Kl + loff0) = k0r;
        *(int4v*)((char*)Kl + loff1) = k1r;
        *(int4v*)((char*)Vl + loff0) = v0r;
        *(int4v*)((char*)Vl + loff1) = v1r;
        __syncthreads();
        if (it + 1 < ntile) {
            const int kv0n = (it + 1) * 64;
            k0r = *(const int4v*)(Kb + (size_t)(kv0n + srow) * ND + scol);
            k1r = *(const int4v*)(Kb + (size_t)(kv0n + srow + 32) * ND + scol);
            v0r = *(const int4v*)(Vb + (size_t)srow * NT + kv0n + scol);
            v1r = *(const int4v*)(Vb + (size_t)(srow + 32) * NT + kv0n + scol);
        }
        if (it > mymax) continue;
        const int kv0 = it * 64;

        // S^T = K.Q^T: lane holds S[kv0+nt*16+lk*4+i][q0+lr]
        f32x4 sa[4];
#pragma unroll
        for (int nt = 0; nt < 4; nt++) sa[nt] = 0.0f;
#pragma unroll
        for (int ks = 0; ks < 2; ks++) {
#pragma unroll
            for (int nt = 0; nt < 4; nt++) {
                const short8 kf = lds_frag(Kl, nt * 16 + lr, ks * 64 + lk * 16);
                sa[nt] = MFMA(kf, qf[ks], sa[nt]);
            }
        }
        // mask + per-lane softmax over this lane's 16 kv values (one q row/lane)
        float sv[4][4];
        float pmax = -1e30f;
#pragma unroll
        for (int nt = 0; nt < 4; nt++) {
            const int kvb = kv0 + nt * 16 + lk * 4;
#pragma unroll
            for (int i = 0; i < 4; i++) {
                const float s = (kvb + i <= q0 + lr) ? sa[nt][i] : -1e30f;
                sv[nt][i] = s;
                pmax = fmaxf(pmax, s);
            }
        }
        pmax = fmaxf(pmax, __shfl_xor(pmax, 16));
        pmax = fmaxf(pmax, __shfl_xor(pmax, 32));
        const float mn = fmaxf(m_s, pmax);
        const float fac = __expf(m_s - mn);
        m_s = mn;
        float ps = 0.0f;
#pragma unroll
        for (int nt = 0; nt < 4; nt++) {
#pragma unroll
            for (int i = 0; i < 4; i++) {
                const float p = __expf(sv[nt][i] - mn);
                sv[nt][i] = p;
                ps += p;
            }
        }
        ps += __shfl_xor(ps, 16);
        ps += __shfl_xor(ps, 32);
        l_s = l_s * fac + ps;
#pragma unroll
        for (int dt = 0; dt < 4; dt++) o[dt] *= fac;
        // P^T -> per-wave LDS (b64 writes), then B-frag reads (b128)
#pragma unroll
        for (int nt = 0; nt < 4; nt++) {
            short4v pk;
#pragma unroll
            for (int i = 0; i < 4; i++) pk[i] = f2bf(sv[nt][i]);
            *(short4v*)(plb + (((lr << 7) + ((nt * 16 + lk * 4) << 1)) ^ ((lr & 7) << 4))) = pk;
        }
        const short8 pb0 = *(const short8*)(plb + (((lr << 7) + ((lk * 8) << 1)) ^ ((lr & 7) << 4)));
        const short8 pb1 = *(const short8*)(plb + (((lr << 7) + ((32 + lk * 8) << 1)) ^ ((lr & 7) << 4)));
        // O^T += V^T . P : lane holds O[d=dt*16+lk*4+i][q0+lr]
#pragma unroll
        for (int ks = 0; ks < 2; ks++) {
            const short8 pb = ks ? pb1 : pb0;
#pragma unroll
            for (int dt = 0; dt < 4; dt++) {
                const short8 vf = lds_frag(Vl, dt * 16 + lr, ks * 64 + lk * 16);
                o[dt] = MFMA(vf, pb, o[dt]);
            }
        }
    }
    const int b = bh >> 4, h = bh & 15;
    const float inv = 1.0f / l_s;
    short* yp = Y + ((size_t)b * NT + (q0 + lr)) * NC + h * ND;
#pragma unroll
    for (int dt = 0; dt < 4; dt++) {
        short4v yk;
#pragma unroll
        for (int i = 0; i < 4; i++) yk[i] = f2bf(o[dt][i] * inv);
        *(short4v*)(yp + dt * 16 + lk * 4) = yk;
    }
}

extern "C" void kernel_launch(void* const* d_in, const int* in_sizes, int n_in,
                              void* d_out, int out_size, void* d_ws, size_t ws_size,
                              hipStream_t stream) {
    const float* x = (const float*)d_in[0];
    const float* qU = (const float*)d_in[1];
    const float* qV = (const float*)d_in[2];
    const float* kU = (const float*)d_in[3];
    const float* kV = (const float*)d_in[4];
    const float* vU = (const float*)d_in[5];
    const float* vV = (const float*)d_in[6];
    const float* cU = (const float*)d_in[7];
    const float* cV = (const float*)d_in[8];
    float* out = (float*)d_out;

    char* ws = (char*)d_ws;
    size_t off = 0;
    auto take = [&](size_t bytes) {
        char* p = ws + off;
        off += (bytes + 255) & ~(size_t)255;
        return p;
    };
    short* Whi = (short*)take(8 * 65536 * 2);
    short* Wlo = (short*)take(8 * 65536 * 2);
    short* Thi3 = (short*)take((size_t)NM * 192 * 2);
    short* Tlov = (short*)take((size_t)NM * 64 * 2);
    short* tyhi = (short*)take((size_t)NM * 64 * 2);
    short* tylo = (short*)take((size_t)NM * 64 * 2);
    short* qb = (short*)take((size_t)NM * NC * 2);
    short* kb = (short*)take((size_t)NM * NC * 2);
    short* vtb = (short*)take((size_t)NM * NC * 2);
    short* yb = (short*)take((size_t)NM * NC * 2);

    const short* qUh = Whi + 4 * 65536;
    const short* kUh = Whi + 5 * 65536;
    const short* vUh = Whi + 6 * 65536;
    const short* vUl = Wlo + 6 * 65536;
    const short* cUh = Whi + 7 * 65536;
    const short* cUl = Wlo + 7 * 65536;

    k_prep<<<dim3(256, 8), 256, 0, stream>>>(qV, kV, vV, cV, qU, kU, vU, cU, Whi, Wlo);
    k_xv3<<<256, 128, 0, stream>>>(x, Whi, Wlo, Thi3, Tlov);
    k_tu<1, 0, 192, 0, 192><<<dim3(128, 4), 256, 0, stream>>>(Thi3, Thi3, qUh, qUh, qb);
    k_tu<1, 0, 192, 64, 192><<<dim3(128, 4), 256, 0, stream>>>(Thi3, Thi3, kUh, kUh, kb);
    k_tu<3, 1, 192, 128, 64><<<dim3(128, 4), 256, 0, stream>>>(Thi3, Tlov, vUh, vUl, vtb);
    k_attn<<<dim3(32, NB * NH), 256, 0, stream>>>(qb, kb, vtb, yb);
    k_yv<<<256, 128, 0, stream>>>(yb, Whi, Wlo, tyhi, tylo);
    k_tu<3, 2, 64, 0, 64><<<dim3(128, 4), 256, 0, stream>>>(tyhi, tylo, cUh, cUl, (void*)out);
}

// Round 5
// 229.811 us; speedup vs baseline: 2.9786x; 1.0672x over previous
//
#include <hip/hip_runtime.h>
#include <hip/hip_bf16.h>
#include <math.h>

// HarmonicCausalSelfAttention: B=4 T=2048 C=1024 H=16 R=64 D=64, alpha=0.7
// R4 pipeline (6 launches):
//   k_prep : split 8 weight mats to bf16 hi/lo; fold s_r into V-mats, 0.125*log2e into qU
//   k_xv   : K-split(4) fused tq|tk|tv partials = x @ Vs^T -> Part[4][8192][192] f32
//   k_tu3  : z=0,1,2 -> q,k ([B,H,T,D]) and v ([B,H,D,T]); sums 4 partials in-register
//   k_attn : causal flash attn, swapped-operand MFMA, exp2-domain softmax,
//            diag-only masking, defer-max (THR=8 log2), single-barrier K/V dbuf
//   k_yv   : K-split(4) ty partials = y @ cVs^T -> PartY[4][8192][64] f32
//   k_tuC  : out = ty @ cU^T (3-term) f32; sums 4 partials in-register

#define NB 4
#define NT 2048
#define NC 1024
#define NH 16
#define NR 64
#define ND 64
#define NM (NB * NT)  // 8192

typedef __attribute__((ext_vector_type(8))) short short8;
typedef __attribute__((ext_vector_type(4))) short short4v;
typedef __attribute__((ext_vector_type(4))) float f32x4;
typedef __attribute__((ext_vector_type(4))) float float4v;
typedef __attribute__((ext_vector_type(4))) int int4v;

__device__ __forceinline__ short f2bf(float f) {
    union { __hip_bfloat16 h; short s; } u;
    u.h = __float2bfloat16(f);
    return u.s;
}
__device__ __forceinline__ float bf2f(short s) {
    union { short s; __hip_bfloat16 h; } u;
    u.s = s;
    return __bfloat162float(u.h);
}
__device__ __forceinline__ f32x4 MFMA(short8 a, short8 b, f32x4 c) {
    return __builtin_amdgcn_mfma_f32_16x16x32_bf16(a, b, c, 0, 0, 0);
}
__device__ __forceinline__ float exp2_(float x) {
#if __has_builtin(__builtin_amdgcn_exp2f)
    return __builtin_amdgcn_exp2f(x);
#else
    return exp2f(x);
#endif
}
__device__ __forceinline__ void ld8_split(const float* __restrict__ p, short8& hi, short8& lo) {
    float4v a = *(const float4v*)p;
    float4v b = *(const float4v*)(p + 4);
    float v[8] = {a[0], a[1], a[2], a[3], b[0], b[1], b[2], b[3]};
#pragma unroll
    for (int j = 0; j < 8; j++) {
        short h = f2bf(v[j]);
        hi[j] = h;
        lo[j] = f2bf(v[j] - bf2f(h));
    }
}

// ---- weight prep: mats 0-3 = qV,kV,vV,cV ([64][1024], scaled by s_row);
//      mats 4-7 = qU,kU,vU,cU ([1024][64]; qU additionally x 0.125*log2e)
__global__ __launch_bounds__(256) void k_prep(const float* __restrict__ qV, const float* __restrict__ kV,
                                              const float* __restrict__ vV, const float* __restrict__ cV,
                                              const float* __restrict__ qU, const float* __restrict__ kU,
                                              const float* __restrict__ vU, const float* __restrict__ cU,
                                              short* __restrict__ Whi, short* __restrict__ Wlo) {
    const int mat = blockIdx.y;
    const int idx = blockIdx.x * 256 + threadIdx.x;
    const float* src;
    switch (mat) {
        case 0: src = qV; break;
        case 1: src = kV; break;
        case 2: src = vV; break;
        case 3: src = cV; break;
        case 4: src = qU; break;
        case 5: src = kU; break;
        case 6: src = vU; break;
        default: src = cU; break;
    }
    float sc = 1.0f;
    if (mat < 4) sc = powf((float)((idx >> 10) + 1), -0.7f);
    if (mat == 4) sc = 0.125f * 1.44269504088896f;  // fold scale and log2(e)
    const float v = src[idx] * sc;
    const short h = f2bf(v);
    Whi[mat * 65536 + idx] = h;
    Wlo[mat * 65536 + idx] = f2bf(v - bf2f(h));
}

// ---- stage 1, K-split: Part[kc][m][p*64+r] partial sums over k in [kc*256,(kc+1)*256)
__global__ __launch_bounds__(256) void k_xv(const float* __restrict__ X,
                                            const short* __restrict__ Whi, const short* __restrict__ Wlo,
                                            float* __restrict__ Part) {
    const int w = threadIdx.x >> 6, l = threadIdx.x & 63;
    const int lr = l & 15, lk = l >> 4;
    const size_t m = (size_t)blockIdx.x * 64 + w * 16 + lr;
    const int kc = blockIdx.y;
    const short* qVh = Whi;
    const short* kVh = Whi + 65536;
    const short* vVh = Whi + 2 * 65536;
    const short* vVl = Wlo + 2 * 65536;

    f32x4 acc[12];
#pragma unroll
    for (int j = 0; j < 12; j++) acc[j] = 0.0f;

    const int kbeg = kc * 256;
    for (int k0 = kbeg; k0 < kbeg + 256; k0 += 32) {
        short8 xh, xl;
        ld8_split(X + m * NC + k0 + lk * 8, xh, xl);
        const int bo = k0 + lk * 8;
#pragma unroll
        for (int nt = 0; nt < 4; nt++) {
            const short8 bq = *(const short8*)(qVh + (size_t)(nt * 16 + lr) * NC + bo);
            acc[nt] = MFMA(xh, bq, acc[nt]);
        }
#pragma unroll
        for (int nt = 0; nt < 4; nt++) {
            const short8 bk = *(const short8*)(kVh + (size_t)(nt * 16 + lr) * NC + bo);
            acc[4 + nt] = MFMA(xh, bk, acc[4 + nt]);
        }
#pragma unroll
        for (int nt = 0; nt < 4; nt++) {
            const short8 bvh = *(const short8*)(vVh + (size_t)(nt * 16 + lr) * NC + bo);
            const short8 bvl = *(const short8*)(vVl + (size_t)(nt * 16 + lr) * NC + bo);
            acc[8 + nt] = MFMA(xh, bvh, acc[8 + nt]);
            acc[8 + nt] = MFMA(xh, bvl, acc[8 + nt]);
            acc[8 + nt] = MFMA(xl, bvh, acc[8 + nt]);
        }
    }
    float* P = Part + (size_t)kc * NM * 192;
    const int mo = blockIdx.x * 64 + w * 16 + lk * 4;
#pragma unroll
    for (int p = 0; p < 3; p++) {
#pragma unroll
        for (int nt = 0; nt < 4; nt++) {
            const int col = p * 64 + nt * 16 + lr;
#pragma unroll
            for (int i = 0; i < 4; i++)
                P[(size_t)(mo + i) * 192 + col] = acc[p * 4 + nt][i];
        }
    }
}

// ---- stage 2 (q,k,v in one launch; z selects): sums 4 K-partials, splits to hi/lo,
// then out[m,n] = T[m,:].U[n,:] (K=64). z<2 -> bf16 [B,H,T,D]; z=2 -> bf16 [B,H,D,T].
__global__ __launch_bounds__(256) void k_tu3(const float* __restrict__ Part,
                                             const short* __restrict__ Whi, const short* __restrict__ Wlo,
                                             short* __restrict__ qb, short* __restrict__ kb,
                                             short* __restrict__ vtb) {
    const int w = threadIdx.x >> 6, l = threadIdx.x & 63;
    const int lr = l & 15, lk = l >> 4;
    const size_t m = (size_t)blockIdx.x * 64 + w * 16 + lr;
    const int n0 = blockIdx.y * 256;
    const int z = blockIdx.z;
    const short* Uh = Whi + (size_t)(4 + z) * 65536;
    const short* Ul = Wlo + (size_t)(4 + z) * 65536;

    short8 ah[2], al[2];
#pragma unroll
    for (int ks = 0; ks < 2; ks++) {
        float sum[8];
        const size_t cbase = m * 192 + z * 64 + ks * 32 + lk * 8;
        {
            const float4v a0 = *(const float4v*)(Part + cbase);
            const float4v b0 = *(const float4v*)(Part + cbase + 4);
#pragma unroll
            for (int j = 0; j < 4; j++) { sum[j] = a0[j]; sum[4 + j] = b0[j]; }
        }
#pragma unroll
        for (int kc = 1; kc < 4; kc++) {
            const float4v a = *(const float4v*)(Part + (size_t)kc * NM * 192 + cbase);
            const float4v b = *(const float4v*)(Part + (size_t)kc * NM * 192 + cbase + 4);
#pragma unroll
            for (int j = 0; j < 4; j++) { sum[j] += a[j]; sum[4 + j] += b[j]; }
        }
#pragma unroll
        for (int j = 0; j < 8; j++) {
            const short h = f2bf(sum[j]);
            ah[ks][j] = h;
            al[ks][j] = f2bf(sum[j] - bf2f(h));
        }
    }
    f32x4 acc[16];
#pragma unroll
    for (int nt = 0; nt < 16; nt++) acc[nt] = 0.0f;
    if (z == 2) {
#pragma unroll
        for (int ks = 0; ks < 2; ks++) {
#pragma unroll
            for (int nt = 0; nt < 16; nt++) {
                const size_t uo = (size_t)(n0 + nt * 16 + lr) * NR + ks * 32 + lk * 8;
                const short8 bh = *(const short8*)(Uh + uo);
                const short8 bl = *(const short8*)(Ul + uo);
                acc[nt] = MFMA(ah[ks], bh, acc[nt]);
                acc[nt] = MFMA(ah[ks], bl, acc[nt]);
                acc[nt] = MFMA(al[ks], bh, acc[nt]);
            }
        }
    } else {
#pragma unroll
        for (int ks = 0; ks < 2; ks++) {
#pragma unroll
            for (int nt = 0; nt < 16; nt++) {
                const size_t uo = (size_t)(n0 + nt * 16 + lr) * NR + ks * 32 + lk * 8;
                const short8 bh = *(const short8*)(Uh + uo);
                acc[nt] = MFMA(ah[ks], bh, acc[nt]);
            }
        }
    }
    const int mo = blockIdx.x * 64 + w * 16 + lk * 4;
    if (z == 2) {  // v: [B,H,D,T], 8B packed stores (tt contiguous per lane)
#pragma unroll
        for (int nt = 0; nt < 16; nt++) {
            const int n = n0 + nt * 16 + lr;
            const int bb = mo >> 11, tt = mo & (NT - 1);
            const int hh = n >> 6, dd = n & 63;
            short4v pk;
#pragma unroll
            for (int i = 0; i < 4; i++) pk[i] = f2bf(acc[nt][i]);
            *(short4v*)(vtb + (((size_t)(bb * NH + hh) * ND + dd) * NT + tt)) = pk;
        }
    } else {
        short* Outp = z ? kb : qb;
#pragma unroll
        for (int nt = 0; nt < 16; nt++) {
            const int n = n0 + nt * 16 + lr;
#pragma unroll
            for (int i = 0; i < 4; i++) {
                const int mm = mo + i;
                const int bb = mm >> 11, tt = mm & (NT - 1);
                const int hh = n >> 6, dd = n & 63;
                Outp[((size_t)(bb * NH + hh) * NT + tt) * ND + dd] = f2bf(acc[nt][i]);
            }
        }
    }
}

// ---- c-path stage 1, K-split: PartY[kc][m][r] = y @ cVs^T partials (2-term)
__global__ __launch_bounds__(256) void k_yv(const short* __restrict__ Yb,
                                            const short* __restrict__ Whi, const short* __restrict__ Wlo,
                                            float* __restrict__ PartY) {
    const int w = threadIdx.x >> 6, l = threadIdx.x & 63;
    const int lr = l & 15, lk = l >> 4;
    const size_t m = (size_t)blockIdx.x * 64 + w * 16 + lr;
    const int kc = blockIdx.y;
    const short* cVh = Whi + 3 * 65536;
    const short* cVl = Wlo + 3 * 65536;

    f32x4 acc[4];
#pragma unroll
    for (int nt = 0; nt < 4; nt++) acc[nt] = 0.0f;

    const int kbeg = kc * 256;
    for (int k0 = kbeg; k0 < kbeg + 256; k0 += 32) {
        const short8 ah = *(const short8*)(Yb + m * NC + k0 + lk * 8);
        const int bo = k0 + lk * 8;
#pragma unroll
        for (int nt = 0; nt < 4; nt++) {
            const short8 bh = *(const short8*)(cVh + (size_t)(nt * 16 + lr) * NC + bo);
            const short8 bl = *(const short8*)(cVl + (size_t)(nt * 16 + lr) * NC + bo);
            acc[nt] = MFMA(ah, bh, acc[nt]);
            acc[nt] = MFMA(ah, bl, acc[nt]);
        }
    }
    float* P = PartY + (size_t)kc * NM * 64;
    const int mo = blockIdx.x * 64 + w * 16 + lk * 4;
#pragma unroll
    for (int nt = 0; nt < 4; nt++) {
        const int col = nt * 16 + lr;
#pragma unroll
        for (int i = 0; i < 4; i++)
            P[(size_t)(mo + i) * 64 + col] = acc[nt][i];
    }
}

// ---- c-path stage 2: out = ty @ cU^T (3-term), sums 4 partials, f32 out [M,C]
__global__ __launch_bounds__(256) void k_tuC(const float* __restrict__ PartY,
                                             const short* __restrict__ Whi, const short* __restrict__ Wlo,
                                             float* __restrict__ Out) {
    const int w = threadIdx.x >> 6, l = threadIdx.x & 63;
    const int lr = l & 15, lk = l >> 4;
    const size_t m = (size_t)blockIdx.x * 64 + w * 16 + lr;
    const int n0 = blockIdx.y * 256;
    const short* Uh = Whi + (size_t)7 * 65536;
    const short* Ul = Wlo + (size_t)7 * 65536;

    short8 ah[2], al[2];
#pragma unroll
    for (int ks = 0; ks < 2; ks++) {
        float sum[8];
        const size_t cbase = m * 64 + ks * 32 + lk * 8;
        {
            const float4v a0 = *(const float4v*)(PartY + cbase);
            const float4v b0 = *(const float4v*)(PartY + cbase + 4);
#pragma unroll
            for (int j = 0; j < 4; j++) { sum[j] = a0[j]; sum[4 + j] = b0[j]; }
        }
#pragma unroll
        for (int kc = 1; kc < 4; kc++) {
            const float4v a = *(const float4v*)(PartY + (size_t)kc * NM * 64 + cbase);
            const float4v b = *(const float4v*)(PartY + (size_t)kc * NM * 64 + cbase + 4);
#pragma unroll
            for (int j = 0; j < 4; j++) { sum[j] += a[j]; sum[4 + j] += b[j]; }
        }
#pragma unroll
        for (int j = 0; j < 8; j++) {
            const short h = f2bf(sum[j]);
            ah[ks][j] = h;
            al[ks][j] = f2bf(sum[j] - bf2f(h));
        }
    }
    f32x4 acc[16];
#pragma unroll
    for (int nt = 0; nt < 16; nt++) acc[nt] = 0.0f;
#pragma unroll
    for (int ks = 0; ks < 2; ks++) {
#pragma unroll
        for (int nt = 0; nt < 16; nt++) {
            const size_t uo = (size_t)(n0 + nt * 16 + lr) * NR + ks * 32 + lk * 8;
            const short8 bh = *(const short8*)(Uh + uo);
            const short8 bl = *(const short8*)(Ul + uo);
            acc[nt] = MFMA(ah[ks], bh, acc[nt]);
            acc[nt] = MFMA(ah[ks], bl, acc[nt]);
            acc[nt] = MFMA(al[ks], bh, acc[nt]);
        }
    }
    const int mo = blockIdx.x * 64 + w * 16 + lk * 4;
#pragma unroll
    for (int nt = 0; nt < 16; nt++) {
        const int n = n0 + nt * 16 + lr;
#pragma unroll
        for (int i = 0; i < 4; i++)
            Out[(size_t)(mo + i) * NC + n] = acc[nt][i];
    }
}

// swizzled LDS fragment read: tile [64][64] bf16, row stride 128B, byte ^ (row&7)<<4
__device__ __forceinline__ short8 lds_frag(const short* base, int row, int cb) {
    return *(const short8*)((const char*)base + (((row << 7) + cb) ^ ((row & 7) << 4)));
}

// ---- causal flash attention, swapped operands, exp2-domain. grid (32, B*H), 4 waves.
// Block j: waves 0,1 -> q rows [32j,32j+32); waves 2,3 -> [2016-32j, 2048-32j).
// Q,K: [B,H,T,D] bf16 (Q pre-scaled by 0.125*log2e). Vt: [B,H,D,T] bf16. Y: [B,T,C] bf16.
__global__ __launch_bounds__(256) void k_attn(const short* __restrict__ Qm,
                                              const short* __restrict__ Km,
                                              const short* __restrict__ Vt,
                                              short* __restrict__ Y) {
    __shared__ __align__(16) short Kl[2][64 * 64];  // 16 KB, double-buffered, swizzled
    __shared__ __align__(16) short Vl[2][64 * 64];  // 16 KB
    __shared__ __align__(16) short Pl[4 * 1024];    // per-wave 16x64 P tile, swizzled
    const int tid = threadIdx.x;
    const int w = tid >> 6, l = tid & 63;
    const int lr = l & 15, lk = l >> 4;
    const int bh = blockIdx.y;
    const int qA0 = blockIdx.x * 32;
    const int qB0 = (NT - 32) - blockIdx.x * 32;
    const int q0 = (w < 2 ? qA0 : qB0) + (w & 1) * 16;
    const int mymax = (q0 + 15) >> 6;         // diagonal (last, masked) kv tile
    const int ntile = ((qB0 + 31) >> 6) + 1;  // tiles staged by the block

    const short* Qp = Qm + ((size_t)bh * NT + q0) * ND;
    short8 qf[2];
#pragma unroll
    for (int ks = 0; ks < 2; ks++)
        qf[ks] = *(const short8*)(Qp + (size_t)lr * ND + ks * 32 + lk * 8);

    const short* Kb = Km + (size_t)bh * NT * ND;
    const short* Vb = Vt + (size_t)bh * ND * NT;

    const int srow = tid >> 3;
    const int scol = (tid & 7) * 8;
    const int loff0 = ((srow << 7) + (scol << 1)) ^ ((srow & 7) << 4);
    const int loff1 = (((srow + 32) << 7) + (scol << 1)) ^ ((srow & 7) << 4);

    float m_s = -1e30f, l_s = 0.0f;
    f32x4 o[4];
#pragma unroll
    for (int dt = 0; dt < 4; dt++) o[dt] = 0.0f;

    char* plb = (char*)Pl + w * 2048;

    int4v k0r = *(const int4v*)(Kb + (size_t)srow * ND + scol);
    int4v k1r = *(const int4v*)(Kb + (size_t)(srow + 32) * ND + scol);
    int4v v0r = *(const int4v*)(Vb + (size_t)srow * NT + scol);
    int4v v1r = *(const int4v*)(Vb + (size_t)(srow + 32) * NT + scol);

    for (int it = 0; it < ntile; ++it) {
        const int buf = it & 1;
        short* KlB = Kl[buf];
        short* VlB = Vl[buf];
        *(int4v*)((char*)KlB + loff0) = k0r;
        *(int4v*)((char*)KlB + loff1) = k1r;
        *(int4v*)((char*)VlB + loff0) = v0r;
        *(int4v*)((char*)VlB + loff1) = v1r;
        if (it + 1 < ntile) {  // prefetch next tile; consumed at next iter's top
            const int kv0n = (it + 1) * 64;
            k0r = *(const int4v*)(Kb + (size_t)(kv0n + srow) * ND + scol);
            k1r = *(const int4v*)(Kb + (size_t)(kv0n + srow + 32) * ND + scol);
            v0r = *(const int4v*)(Vb + (size_t)srow * NT + kv0n + scol);
            v1r = *(const int4v*)(Vb + (size_t)(srow + 32) * NT + kv0n + scol);
        }
        __syncthreads();  // single barrier per tile (dbuf makes it safe)
        if (it > mymax) continue;
        const int kv0 = it * 64;

        // S^T = K.Q^T (log2 domain): lane holds S[kv0+nt*16+lk*4+i][q0+lr]
        f32x4 sa[4];
#pragma unroll
        for (int nt = 0; nt < 4; nt++) sa[nt] = 0.0f;
        __builtin_amdgcn_s_setprio(1);
#pragma unroll
        for (int ks = 0; ks < 2; ks++) {
#pragma unroll
            for (int nt = 0; nt < 4; nt++) {
                const short8 kf = lds_frag(KlB, nt * 16 + lr, ks * 64 + lk * 16);
                sa[nt] = MFMA(kf, qf[ks], sa[nt]);
            }
        }
        __builtin_amdgcn_s_setprio(0);
        // mask only on the diagonal tile; per-lane softmax (one q row per lane)
        float sv[4][4];
        if (it == mymax) {
#pragma unroll
            for (int nt = 0; nt < 4; nt++) {
                const int kvb = kv0 + nt * 16 + lk * 4;
#pragma unroll
                for (int i = 0; i < 4; i++)
                    sv[nt][i] = (kvb + i <= q0 + lr) ? sa[nt][i] : -1e30f;
            }
        } else {
#pragma unroll
            for (int nt = 0; nt < 4; nt++) {
#pragma unroll
                for (int i = 0; i < 4; i++) sv[nt][i] = sa[nt][i];
            }
        }
        float tmx[4];
#pragma unroll
        for (int nt = 0; nt < 4; nt++)
            tmx[nt] = fmaxf(fmaxf(fmaxf(sv[nt][0], sv[nt][1]), sv[nt][2]), sv[nt][3]);
        float pmax = fmaxf(fmaxf(fmaxf(tmx[0], tmx[1]), tmx[2]), tmx[3]);
        pmax = fmaxf(pmax, __shfl_xor(pmax, 16));
        pmax = fmaxf(pmax, __shfl_xor(pmax, 32));
        // defer-max: rescale only when a row's max grew by more than 2^8
        if (!__all(pmax - m_s <= 8.0f)) {
            const float mn = fmaxf(m_s, pmax);
            const float fc = exp2_(m_s - mn);
            m_s = mn;
            l_s *= fc;
#pragma unroll
            for (int dt = 0; dt < 4; dt++) o[dt] *= fc;
        }
        float psn[4];
#pragma unroll
        for (int nt = 0; nt < 4; nt++) {
#pragma unroll
            for (int i = 0; i < 4; i++) sv[nt][i] = exp2_(sv[nt][i] - m_s);
            psn[nt] = (sv[nt][0] + sv[nt][1]) + (sv[nt][2] + sv[nt][3]);
        }
        float ps = (psn[0] + psn[1]) + (psn[2] + psn[3]);
        ps += __shfl_xor(ps, 16);
        ps += __shfl_xor(ps, 32);
        l_s += ps;
        // P^T -> per-wave LDS (b64 writes), then B-frag reads (b128)
#pragma unroll
        for (int nt = 0; nt < 4; nt++) {
            short4v pk;
#pragma unroll
            for (int i = 0; i < 4; i++) pk[i] = f2bf(sv[nt][i]);
            *(short4v*)(plb + (((lr << 7) + ((nt * 16 + lk * 4) << 1)) ^ ((lr & 7) << 4))) = pk;
        }
        const short8 pb0 = *(const short8*)(plb + (((lr << 7) + ((lk * 8) << 1)) ^ ((lr & 7) << 4)));
        const short8 pb1 = *(const short8*)(plb + (((lr << 7) + ((32 + lk * 8) << 1)) ^ ((lr & 7) << 4)));
        // O^T += V^T . P : lane holds O[d=dt*16+lk*4+i][q0+lr]
        __builtin_amdgcn_s_setprio(1);
#pragma unroll
        for (int ks = 0; ks < 2; ks++) {
            const short8 pb = ks ? pb1 : pb0;
#pragma unroll
            for (int dt = 0; dt < 4; dt++) {
                const short8 vf = lds_frag(VlB, dt * 16 + lr, ks * 64 + lk * 16);
                o[dt] = MFMA(vf, pb, o[dt]);
            }
        }
        __builtin_amdgcn_s_setprio(0);
    }
    const int b = bh >> 4, h = bh & 15;
    const float inv = 1.0f / l_s;
    short* yp = Y + ((size_t)b * NT + (q0 + lr)) * NC + h * ND;
#pragma unroll
    for (int dt = 0; dt < 4; dt++) {
        short4v yk;
#pragma unroll
        for (int i = 0; i < 4; i++) yk[i] = f2bf(o[dt][i] * inv);
        *(short4v*)(yp + dt * 16 + lk * 4) = yk;
    }
}

extern "C" void kernel_launch(void* const* d_in, const int* in_sizes, int n_in,
                              void* d_out, int out_size, void* d_ws, size_t ws_size,
                              hipStream_t stream) {
    const float* x = (const float*)d_in[0];
    const float* qU = (const float*)d_in[1];
    const float* qV = (const float*)d_in[2];
    const float* kU = (const float*)d_in[3];
    const float* kV = (const float*)d_in[4];
    const float* vU = (const float*)d_in[5];
    const float* vV = (const float*)d_in[6];
    const float* cU = (const float*)d_in[7];
    const float* cV = (const float*)d_in[8];
    float* out = (float*)d_out;

    char* ws = (char*)d_ws;
    size_t off = 0;
    auto take = [&](size_t bytes) {
        char* p = ws + off;
        off += (bytes + 255) & ~(size_t)255;
        return p;
    };
    short* Whi = (short*)take(8 * 65536 * 2);
    short* Wlo = (short*)take(8 * 65536 * 2);
    float* Part = (float*)take((size_t)4 * NM * 192 * 4);  // 25.2 MB; reused below
    short* qb = (short*)take((size_t)NM * NC * 2);
    short* kb = (short*)take((size_t)NM * NC * 2);
    short* vtb = (short*)take((size_t)NM * NC * 2);
    // aliases inside Part (Part is dead after k_tu3): yb 16.8MB, PartY 8.4MB
    short* yb = (short*)Part;
    float* PartY = (float*)((char*)Part + (size_t)NM * NC * 2);

    k_prep<<<dim3(256, 8), 256, 0, stream>>>(qV, kV, vV, cV, qU, kU, vU, cU, Whi, Wlo);
    k_xv<<<dim3(128, 4), 256, 0, stream>>>(x, Whi, Wlo, Part);
    k_tu3<<<dim3(128, 4, 3), 256, 0, stream>>>(Part, Whi, Wlo, qb, kb, vtb);
    k_attn<<<dim3(32, NB * NH), 256, 0, stream>>>(qb, kb, vtb, yb);
    k_yv<<<dim3(128, 4), 256, 0, stream>>>(yb, Whi, Wlo, PartY);
    k_tuC<<<dim3(128, 4), 256, 0, stream>>>(PartY, Whi, Wlo, out);
}

// Round 6
// 198.527 us; speedup vs baseline: 3.4479x; 1.1576x over previous
//
#include <hip/hip_runtime.h>
#include <hip/hip_bf16.h>
#include <math.h>

// HarmonicCausalSelfAttention: B=4 T=2048 C=1024 H=16 R=64 D=64, alpha=0.7
// R5 pipeline (6 launches):
//   k_prep : split 8 weight mats to bf16 hi/lo; fold s_r into V-mats, 0.125*log2e into qU
//   k_xv   : K-split(4) fused tq|tk|tv partials = x @ Vs^T -> Part[4][8192][192] f32
//   k_tu3  : z=0,1,2 -> q,k ([B,H,T,D]) and v ([B,H,D,T]); sums 4 partials once,
//            loops 2 n0-halves (halves Part HBM re-reads)
//   k_attn : causal flash attn; each wave owns a low-q AND a high-q 16-row group
//            (uniform work per wave); global_load_lds staging with pre-swizzled
//            source; XCD-chunked block swizzle; exp2 softmax, defer-max
//   k_yv   : K-split(4) ty partials = y @ cVs^T -> PartY[4][8192][64] f32
//   k_tuC  : out = ty @ cU^T (3-term) f32; sums partials once, loops 2 n0-halves

#define NB 4
#define NT 2048
#define NC 1024
#define NH 16
#define NR 64
#define ND 64
#define NM (NB * NT)  // 8192

typedef __attribute__((ext_vector_type(8))) short short8;
typedef __attribute__((ext_vector_type(4))) short short4v;
typedef __attribute__((ext_vector_type(4))) float f32x4;
typedef __attribute__((ext_vector_type(4))) float float4v;
typedef __attribute__((ext_vector_type(4))) int int4v;

__device__ __forceinline__ short f2bf(float f) {
    union { __hip_bfloat16 h; short s; } u;
    u.h = __float2bfloat16(f);
    return u.s;
}
__device__ __forceinline__ float bf2f(short s) {
    union { short s; __hip_bfloat16 h; } u;
    u.s = s;
    return __bfloat162float(u.h);
}
__device__ __forceinline__ f32x4 MFMA(short8 a, short8 b, f32x4 c) {
    return __builtin_amdgcn_mfma_f32_16x16x32_bf16(a, b, c, 0, 0, 0);
}
__device__ __forceinline__ float exp2_(float x) {
#if __has_builtin(__builtin_amdgcn_exp2f)
    return __builtin_amdgcn_exp2f(x);
#else
    return exp2f(x);
#endif
}
__device__ __forceinline__ void ld8_split(const float* __restrict__ p, short8& hi, short8& lo) {
    float4v a = *(const float4v*)p;
    float4v b = *(const float4v*)(p + 4);
    float v[8] = {a[0], a[1], a[2], a[3], b[0], b[1], b[2], b[3]};
#pragma unroll
    for (int j = 0; j < 8; j++) {
        short h = f2bf(v[j]);
        hi[j] = h;
        lo[j] = f2bf(v[j] - bf2f(h));
    }
}

// async global->LDS, 16B per lane (LDS dest = wave-uniform base + lane*16)
typedef const __attribute__((address_space(1))) unsigned int* gas_ptr;
typedef __attribute__((address_space(3))) unsigned int* las_ptr;
__device__ __forceinline__ void gll16(const void* g, void* l) {
    __builtin_amdgcn_global_load_lds((gas_ptr)g, (las_ptr)l, 16, 0, 0);
}

// ---- weight prep: mats 0-3 = qV,kV,vV,cV ([64][1024], scaled by s_row);
//      mats 4-7 = qU,kU,vU,cU ([1024][64]; qU additionally x 0.125*log2e)
__global__ __launch_bounds__(256) void k_prep(const float* __restrict__ qV, const float* __restrict__ kV,
                                              const float* __restrict__ vV, const float* __restrict__ cV,
                                              const float* __restrict__ qU, const float* __restrict__ kU,
                                              const float* __restrict__ vU, const float* __restrict__ cU,
                                              short* __restrict__ Whi, short* __restrict__ Wlo) {
    const int mat = blockIdx.y;
    const int idx = blockIdx.x * 256 + threadIdx.x;
    const float* src;
    switch (mat) {
        case 0: src = qV; break;
        case 1: src = kV; break;
        case 2: src = vV; break;
        case 3: src = cV; break;
        case 4: src = qU; break;
        case 5: src = kU; break;
        case 6: src = vU; break;
        default: src = cU; break;
    }
    float sc = 1.0f;
    if (mat < 4) sc = powf((float)((idx >> 10) + 1), -0.7f);
    if (mat == 4) sc = 0.125f * 1.44269504088896f;  // fold scale and log2(e)
    const float v = src[idx] * sc;
    const short h = f2bf(v);
    Whi[mat * 65536 + idx] = h;
    Wlo[mat * 65536 + idx] = f2bf(v - bf2f(h));
}

// ---- stage 1, K-split: Part[kc][m][p*64+r] partial sums over k in [kc*256,(kc+1)*256)
__global__ __launch_bounds__(256) void k_xv(const float* __restrict__ X,
                                            const short* __restrict__ Whi, const short* __restrict__ Wlo,
                                            float* __restrict__ Part) {
    const int w = threadIdx.x >> 6, l = threadIdx.x & 63;
    const int lr = l & 15, lk = l >> 4;
    const size_t m = (size_t)blockIdx.x * 64 + w * 16 + lr;
    const int kc = blockIdx.y;
    const short* qVh = Whi;
    const short* kVh = Whi + 65536;
    const short* vVh = Whi + 2 * 65536;
    const short* vVl = Wlo + 2 * 65536;

    f32x4 acc[12];
#pragma unroll
    for (int j = 0; j < 12; j++) acc[j] = 0.0f;

    const int kbeg = kc * 256;
    for (int k0 = kbeg; k0 < kbeg + 256; k0 += 32) {
        short8 xh, xl;
        ld8_split(X + m * NC + k0 + lk * 8, xh, xl);
        const int bo = k0 + lk * 8;
#pragma unroll
        for (int nt = 0; nt < 4; nt++) {
            const short8 bq = *(const short8*)(qVh + (size_t)(nt * 16 + lr) * NC + bo);
            acc[nt] = MFMA(xh, bq, acc[nt]);
        }
#pragma unroll
        for (int nt = 0; nt < 4; nt++) {
            const short8 bk = *(const short8*)(kVh + (size_t)(nt * 16 + lr) * NC + bo);
            acc[4 + nt] = MFMA(xh, bk, acc[4 + nt]);
        }
#pragma unroll
        for (int nt = 0; nt < 4; nt++) {
            const short8 bvh = *(const short8*)(vVh + (size_t)(nt * 16 + lr) * NC + bo);
            const short8 bvl = *(const short8*)(vVl + (size_t)(nt * 16 + lr) * NC + bo);
            acc[8 + nt] = MFMA(xh, bvh, acc[8 + nt]);
            acc[8 + nt] = MFMA(xh, bvl, acc[8 + nt]);
            acc[8 + nt] = MFMA(xl, bvh, acc[8 + nt]);
        }
    }
    float* P = Part + (size_t)kc * NM * 192;
    const int mo = blockIdx.x * 64 + w * 16 + lk * 4;
#pragma unroll
    for (int p = 0; p < 3; p++) {
#pragma unroll
        for (int nt = 0; nt < 4; nt++) {
            const int col = p * 64 + nt * 16 + lr;
#pragma unroll
            for (int i = 0; i < 4; i++)
                P[(size_t)(mo + i) * 192 + col] = acc[p * 4 + nt][i];
        }
    }
}

// ---- stage 2 (q,k,v; z selects): sums 4 K-partials once, loops 2 n0-halves.
// z<2 -> bf16 [B,H,T,D]; z=2 -> bf16 [B,H,D,T].
__global__ __launch_bounds__(256) void k_tu3(const float* __restrict__ Part,
                                             const short* __restrict__ Whi, const short* __restrict__ Wlo,
                                             short* __restrict__ qb, short* __restrict__ kb,
                                             short* __restrict__ vtb) {
    const int w = threadIdx.x >> 6, l = threadIdx.x & 63;
    const int lr = l & 15, lk = l >> 4;
    const size_t m = (size_t)blockIdx.x * 64 + w * 16 + lr;
    const int z = blockIdx.z;
    const short* Uh = Whi + (size_t)(4 + z) * 65536;
    const short* Ul = Wlo + (size_t)(4 + z) * 65536;

    short8 ah[2], al[2];
#pragma unroll
    for (int ks = 0; ks < 2; ks++) {
        float sum[8];
        const size_t cbase = m * 192 + z * 64 + ks * 32 + lk * 8;
        {
            const float4v a0 = *(const float4v*)(Part + cbase);
            const float4v b0 = *(const float4v*)(Part + cbase + 4);
#pragma unroll
            for (int j = 0; j < 4; j++) { sum[j] = a0[j]; sum[4 + j] = b0[j]; }
        }
#pragma unroll
        for (int kc = 1; kc < 4; kc++) {
            const float4v a = *(const float4v*)(Part + (size_t)kc * NM * 192 + cbase);
            const float4v b = *(const float4v*)(Part + (size_t)kc * NM * 192 + cbase + 4);
#pragma unroll
            for (int j = 0; j < 4; j++) { sum[j] += a[j]; sum[4 + j] += b[j]; }
        }
#pragma unroll
        for (int j = 0; j < 8; j++) {
            const short h = f2bf(sum[j]);
            ah[ks][j] = h;
            al[ks][j] = f2bf(sum[j] - bf2f(h));
        }
    }
    const int mo = blockIdx.x * 64 + w * 16 + lk * 4;
    for (int yy = 0; yy < 2; yy++) {
        const int n0 = (blockIdx.y * 2 + yy) * 256;
        f32x4 acc[16];
#pragma unroll
        for (int nt = 0; nt < 16; nt++) acc[nt] = 0.0f;
        if (z == 2) {
#pragma unroll
            for (int ks = 0; ks < 2; ks++) {
#pragma unroll
                for (int nt = 0; nt < 16; nt++) {
                    const size_t uo = (size_t)(n0 + nt * 16 + lr) * NR + ks * 32 + lk * 8;
                    const short8 bh = *(const short8*)(Uh + uo);
                    const short8 bl = *(const short8*)(Ul + uo);
                    acc[nt] = MFMA(ah[ks], bh, acc[nt]);
                    acc[nt] = MFMA(ah[ks], bl, acc[nt]);
                    acc[nt] = MFMA(al[ks], bh, acc[nt]);
                }
            }
        } else {
#pragma unroll
            for (int ks = 0; ks < 2; ks++) {
#pragma unroll
                for (int nt = 0; nt < 16; nt++) {
                    const size_t uo = (size_t)(n0 + nt * 16 + lr) * NR + ks * 32 + lk * 8;
                    const short8 bh = *(const short8*)(Uh + uo);
                    acc[nt] = MFMA(ah[ks], bh, acc[nt]);
                }
            }
        }
        if (z == 2) {  // v: [B,H,D,T], 8B packed stores (tt contiguous per lane)
#pragma unroll
            for (int nt = 0; nt < 16; nt++) {
                const int n = n0 + nt * 16 + lr;
                const int bb = mo >> 11, tt = mo & (NT - 1);
                const int hh = n >> 6, dd = n & 63;
                short4v pk;
#pragma unroll
                for (int i = 0; i < 4; i++) pk[i] = f2bf(acc[nt][i]);
                *(short4v*)(vtb + (((size_t)(bb * NH + hh) * ND + dd) * NT + tt)) = pk;
            }
        } else {
            short* Outp = z ? kb : qb;
#pragma unroll
            for (int nt = 0; nt < 16; nt++) {
                const int n = n0 + nt * 16 + lr;
#pragma unroll
                for (int i = 0; i < 4; i++) {
                    const int mm = mo + i;
                    const int bb = mm >> 11, tt = mm & (NT - 1);
                    const int hh = n >> 6, dd = n & 63;
                    Outp[((size_t)(bb * NH + hh) * NT + tt) * ND + dd] = f2bf(acc[nt][i]);
                }
            }
        }
    }
}

// ---- c-path stage 1, K-split: PartY[kc][m][r] = y @ cVs^T partials (2-term)
__global__ __launch_bounds__(256) void k_yv(const short* __restrict__ Yb,
                                            const short* __restrict__ Whi, const short* __restrict__ Wlo,
                                            float* __restrict__ PartY) {
    const int w = threadIdx.x >> 6, l = threadIdx.x & 63;
    const int lr = l & 15, lk = l >> 4;
    const size_t m = (size_t)blockIdx.x * 64 + w * 16 + lr;
    const int kc = blockIdx.y;
    const short* cVh = Whi + 3 * 65536;
    const short* cVl = Wlo + 3 * 65536;

    f32x4 acc[4];
#pragma unroll
    for (int nt = 0; nt < 4; nt++) acc[nt] = 0.0f;

    const int kbeg = kc * 256;
    for (int k0 = kbeg; k0 < kbeg + 256; k0 += 32) {
        const short8 ah = *(const short8*)(Yb + m * NC + k0 + lk * 8);
        const int bo = k0 + lk * 8;
#pragma unroll
        for (int nt = 0; nt < 4; nt++) {
            const short8 bh = *(const short8*)(cVh + (size_t)(nt * 16 + lr) * NC + bo);
            const short8 bl = *(const short8*)(cVl + (size_t)(nt * 16 + lr) * NC + bo);
            acc[nt] = MFMA(ah, bh, acc[nt]);
            acc[nt] = MFMA(ah, bl, acc[nt]);
        }
    }
    float* P = PartY + (size_t)kc * NM * 64;
    const int mo = blockIdx.x * 64 + w * 16 + lk * 4;
#pragma unroll
    for (int nt = 0; nt < 4; nt++) {
        const int col = nt * 16 + lr;
#pragma unroll
        for (int i = 0; i < 4; i++)
            P[(size_t)(mo + i) * 64 + col] = acc[nt][i];
    }
}

// ---- c-path stage 2: out = ty @ cU^T (3-term), sums partials once, 2 n0-halves
__global__ __launch_bounds__(256) void k_tuC(const float* __restrict__ PartY,
                                             const short* __restrict__ Whi, const short* __restrict__ Wlo,
                                             float* __restrict__ Out) {
    const int w = threadIdx.x >> 6, l = threadIdx.x & 63;
    const int lr = l & 15, lk = l >> 4;
    const size_t m = (size_t)blockIdx.x * 64 + w * 16 + lr;
    const short* Uh = Whi + (size_t)7 * 65536;
    const short* Ul = Wlo + (size_t)7 * 65536;

    short8 ah[2], al[2];
#pragma unroll
    for (int ks = 0; ks < 2; ks++) {
        float sum[8];
        const size_t cbase = m * 64 + ks * 32 + lk * 8;
        {
            const float4v a0 = *(const float4v*)(PartY + cbase);
            const float4v b0 = *(const float4v*)(PartY + cbase + 4);
#pragma unroll
            for (int j = 0; j < 4; j++) { sum[j] = a0[j]; sum[4 + j] = b0[j]; }
        }
#pragma unroll
        for (int kc = 1; kc < 4; kc++) {
            const float4v a = *(const float4v*)(PartY + (size_t)kc * NM * 64 + cbase);
            const float4v b = *(const float4v*)(PartY + (size_t)kc * NM * 64 + cbase + 4);
#pragma unroll
            for (int j = 0; j < 4; j++) { sum[j] += a[j]; sum[4 + j] += b[j]; }
        }
#pragma unroll
        for (int j = 0; j < 8; j++) {
            const short h = f2bf(sum[j]);
            ah[ks][j] = h;
            al[ks][j] = f2bf(sum[j] - bf2f(h));
        }
    }
    const int mo = blockIdx.x * 64 + w * 16 + lk * 4;
    for (int yy = 0; yy < 2; yy++) {
        const int n0 = (blockIdx.y * 2 + yy) * 256;
        f32x4 acc[16];
#pragma unroll
        for (int nt = 0; nt < 16; nt++) acc[nt] = 0.0f;
#pragma unroll
        for (int ks = 0; ks < 2; ks++) {
#pragma unroll
            for (int nt = 0; nt < 16; nt++) {
                const size_t uo = (size_t)(n0 + nt * 16 + lr) * NR + ks * 32 + lk * 8;
                const short8 bh = *(const short8*)(Uh + uo);
                const short8 bl = *(const short8*)(Ul + uo);
                acc[nt] = MFMA(ah[ks], bh, acc[nt]);
                acc[nt] = MFMA(ah[ks], bl, acc[nt]);
                acc[nt] = MFMA(al[ks], bh, acc[nt]);
            }
        }
#pragma unroll
        for (int nt = 0; nt < 16; nt++) {
            const int n = n0 + nt * 16 + lr;
#pragma unroll
            for (int i = 0; i < 4; i++)
                Out[(size_t)(mo + i) * NC + n] = acc[nt][i];
        }
    }
}

// swizzled LDS fragment read: tile [64][64] bf16, row stride 128B, byte ^ (row&7)<<4
__device__ __forceinline__ short8 lds_frag(const short* base, int row, int cb) {
    return *(const short8*)((const char*)base + (((row << 7) + cb) ^ ((row & 7) << 4)));
}

// ---- causal flash attention. grid (16, B*H) XCD-swizzled; 4 waves/block.
// Block j covers q rows [64j,64j+64) (A) and [2048-64(j+1), 2048-64j) (B);
// wave w owns 16 rows of EACH -> uniform 33 computes per wave.
// Q,K: [B,H,T,D] bf16 (Q pre-scaled by 0.125*log2e). Vt: [B,H,D,T] bf16. Y: [B,T,C] bf16.
__global__ __launch_bounds__(256, 4) void k_attn(const short* __restrict__ Qm,
                                                 const short* __restrict__ Km,
                                                 const short* __restrict__ Vt,
                                                 short* __restrict__ Y) {
    __shared__ __align__(16) short Kl[2][64 * 64];  // 16 KB dbuf, swizzled layout
    __shared__ __align__(16) short Vl[2][64 * 64];  // 16 KB
    __shared__ __align__(16) short Pl[4 * 1024];    // per-wave 16x64 P tile, swizzled
    const int tid = threadIdx.x;
    const int w = tid >> 6, l = tid & 63;
    const int lr = l & 15, lk = l >> 4;
    // bijective XCD-chunk swizzle: each XCD gets 8 complete bh's (K/V L2-resident)
    const int lin = blockIdx.y * 16 + blockIdx.x;
    const int nl = (lin & 7) * 128 + (lin >> 3);
    const int j = nl & 15;
    const int bh = nl >> 4;
    const int ntile = 32 - j;
    const int qA = 64 * j + w * 16;
    const int qB = (NT - 64 * (j + 1)) + w * 16;
    const int qrel = w * 16 + lr;  // diag-tile mask threshold (same for A and B)

    const short* Kb = Km + (size_t)bh * NT * ND;
    const short* Vb = Vt + (size_t)bh * ND * NT;

    short8 qfA[2], qfB[2];
#pragma unroll
    for (int ks = 0; ks < 2; ks++) {
        qfA[ks] = *(const short8*)(Qm + ((size_t)bh * NT + qA + lr) * ND + ks * 32 + lk * 8);
        qfB[ks] = *(const short8*)(Qm + ((size_t)bh * NT + qB + lr) * ND + ks * 32 + lk * 8);
    }

    // global_load_lds staging: LDS dest linear (wave base + lane*16); global src
    // pre-swizzled so swizzled reads see the right data (inverse of read XOR).
    const int grow8 = w * 8 + (l >> 3);                       // row within 32-row chunk
    const int gcolb = (((l & 7) ^ ((l >> 3) & 7)) << 4);      // byte col within row
    auto stage = [&](int buf, int kv0) {
        const char* kp = (const char*)Kb + (((size_t)(kv0 + grow8)) << 7) + gcolb;
        const char* vp = (const char*)Vb + (size_t)grow8 * (NT * 2) + kv0 * 2 + gcolb;
        char* kl = (char*)Kl[buf] + w * 1024;
        char* vl = (char*)Vl[buf] + w * 1024;
        gll16(kp, kl);
        gll16(kp + (32 << 7), kl + 4096);
        gll16(vp, vl);
        gll16(vp + (size_t)32 * NT * 2, vl + 4096);
    };

    float m_sA = -1e30f, l_sA = 0.0f, m_sB = -1e30f, l_sB = 0.0f;
    f32x4 oA[4], oB[4];
#pragma unroll
    for (int dt = 0; dt < 4; dt++) { oA[dt] = 0.0f; oB[dt] = 0.0f; }

    char* plb = (char*)Pl + w * 2048;

    auto compute = [&](const short8* qf, float& m_s, float& l_s, f32x4* o,
                       const short* KlB, const short* VlB, bool diag) {
        f32x4 sa[4];
#pragma unroll
        for (int nt = 0; nt < 4; nt++) sa[nt] = 0.0f;
        __builtin_amdgcn_s_setprio(1);
#pragma unroll
        for (int ks = 0; ks < 2; ks++) {
#pragma unroll
            for (int nt = 0; nt < 4; nt++) {
                const short8 kf = lds_frag(KlB, nt * 16 + lr, ks * 64 + lk * 16);
                sa[nt] = MFMA(kf, qf[ks], sa[nt]);
            }
        }
        __builtin_amdgcn_s_setprio(0);
        float sv[4][4];
        if (diag) {
#pragma unroll
            for (int nt = 0; nt < 4; nt++) {
                const int kvb = nt * 16 + lk * 4;
#pragma unroll
                for (int i = 0; i < 4; i++)
                    sv[nt][i] = (kvb + i <= qrel) ? sa[nt][i] : -1e30f;
            }
        } else {
#pragma unroll
            for (int nt = 0; nt < 4; nt++) {
#pragma unroll
                for (int i = 0; i < 4; i++) sv[nt][i] = sa[nt][i];
            }
        }
        float tmx[4];
#pragma unroll
        for (int nt = 0; nt < 4; nt++)
            tmx[nt] = fmaxf(fmaxf(fmaxf(sv[nt][0], sv[nt][1]), sv[nt][2]), sv[nt][3]);
        float pmax = fmaxf(fmaxf(fmaxf(tmx[0], tmx[1]), tmx[2]), tmx[3]);
        pmax = fmaxf(pmax, __shfl_xor(pmax, 16));
        pmax = fmaxf(pmax, __shfl_xor(pmax, 32));
        if (!__all(pmax - m_s <= 8.0f)) {  // defer-max (log2 domain)
            const float mn = fmaxf(m_s, pmax);
            const float fc = exp2_(m_s - mn);
            m_s = mn;
            l_s *= fc;
#pragma unroll
            for (int dt = 0; dt < 4; dt++) o[dt] *= fc;
        }
        float psn[4];
#pragma unroll
        for (int nt = 0; nt < 4; nt++) {
#pragma unroll
            for (int i = 0; i < 4; i++) sv[nt][i] = exp2_(sv[nt][i] - m_s);
            psn[nt] = (sv[nt][0] + sv[nt][1]) + (sv[nt][2] + sv[nt][3]);
        }
        float ps = (psn[0] + psn[1]) + (psn[2] + psn[3]);
        ps += __shfl_xor(ps, 16);
        ps += __shfl_xor(ps, 32);
        l_s += ps;
        // P^T -> per-wave LDS (b64 writes), then B-frag reads (b128)
#pragma unroll
        for (int nt = 0; nt < 4; nt++) {
            short4v pk;
#pragma unroll
            for (int i = 0; i < 4; i++) pk[i] = f2bf(sv[nt][i]);
            *(short4v*)(plb + (((lr << 7) + ((nt * 16 + lk * 4) << 1)) ^ ((lr & 7) << 4))) = pk;
        }
        const short8 pb0 = *(const short8*)(plb + (((lr << 7) + ((lk * 8) << 1)) ^ ((lr & 7) << 4)));
        const short8 pb1 = *(const short8*)(plb + (((lr << 7) + ((32 + lk * 8) << 1)) ^ ((lr & 7) << 4)));
        __builtin_amdgcn_s_setprio(1);
#pragma unroll
        for (int ks = 0; ks < 2; ks++) {
            const short8 pb = ks ? pb1 : pb0;
#pragma unroll
            for (int dt = 0; dt < 4; dt++) {
                const short8 vf = lds_frag(VlB, dt * 16 + lr, ks * 64 + lk * 16);
                o[dt] = MFMA(vf, pb, o[dt]);
            }
        }
        __builtin_amdgcn_s_setprio(0);
    };

    stage(0, 0);  // tile 0 -> buf 0
    for (int it = 0; it < ntile; ++it) {
        const int buf = it & 1;
        __syncthreads();  // drains this tile's global_load_lds (vmcnt) + syncs
        if (it + 1 < ntile) stage(buf ^ 1, (it + 1) * 64);  // overlaps compute below
        const short* KlB = Kl[buf];
        const short* VlB = Vl[buf];
        if (it <= j) compute(qfA, m_sA, l_sA, oA, KlB, VlB, it == j);
        compute(qfB, m_sB, l_sB, oB, KlB, VlB, it == ntile - 1);
    }

    const int b = bh >> 4, h = bh & 15;
    const float invA = 1.0f / l_sA, invB = 1.0f / l_sB;
    short* ypA = Y + ((size_t)b * NT + (qA + lr)) * NC + h * ND;
    short* ypB = Y + ((size_t)b * NT + (qB + lr)) * NC + h * ND;
#pragma unroll
    for (int dt = 0; dt < 4; dt++) {
        short4v ya, yb2;
#pragma unroll
        for (int i = 0; i < 4; i++) {
            ya[i] = f2bf(oA[dt][i] * invA);
            yb2[i] = f2bf(oB[dt][i] * invB);
        }
        *(short4v*)(ypA + dt * 16 + lk * 4) = ya;
        *(short4v*)(ypB + dt * 16 + lk * 4) = yb2;
    }
}

extern "C" void kernel_launch(void* const* d_in, const int* in_sizes, int n_in,
                              void* d_out, int out_size, void* d_ws, size_t ws_size,
                              hipStream_t stream) {
    const float* x = (const float*)d_in[0];
    const float* qU = (const float*)d_in[1];
    const float* qV = (const float*)d_in[2];
    const float* kU = (const float*)d_in[3];
    const float* kV = (const float*)d_in[4];
    const float* vU = (const float*)d_in[5];
    const float* vV = (const float*)d_in[6];
    const float* cU = (const float*)d_in[7];
    const float* cV = (const float*)d_in[8];
    float* out = (float*)d_out;

    char* ws = (char*)d_ws;
    size_t off = 0;
    auto take = [&](size_t bytes) {
        char* p = ws + off;
        off += (bytes + 255) & ~(size_t)255;
        return p;
    };
    short* Whi = (short*)take(8 * 65536 * 2);
    short* Wlo = (short*)take(8 * 65536 * 2);
    float* Part = (float*)take((size_t)4 * NM * 192 * 4);  // 25.2 MB; reused below
    short* qb = (short*)take((size_t)NM * NC * 2);
    short* kb = (short*)take((size_t)NM * NC * 2);
    short* vtb = (short*)take((size_t)NM * NC * 2);
    // aliases inside Part (Part is dead after k_tu3): yb 16.8MB, PartY 8.4MB
    short* yb = (short*)Part;
    float* PartY = (float*)((char*)Part + (size_t)NM * NC * 2);

    k_prep<<<dim3(256, 8), 256, 0, stream>>>(qV, kV, vV, cV, qU, kU, vU, cU, Whi, Wlo);
    k_xv<<<dim3(128, 4), 256, 0, stream>>>(x, Whi, Wlo, Part);
    k_tu3<<<dim3(128, 2, 3), 256, 0, stream>>>(Part, Whi, Wlo, qb, kb, vtb);
    k_attn<<<dim3(16, NB * NH), 256, 0, stream>>>(qb, kb, vtb, yb);
    k_yv<<<dim3(128, 4), 256, 0, stream>>>(yb, Whi, Wlo, PartY);
    k_tuC<<<dim3(128, 2), 256, 0, stream>>>(PartY, Whi, Wlo, out);
}

// Round 7
// 170.407 us; speedup vs baseline: 4.0169x; 1.1650x over previous
//
#include <hip/hip_runtime.h>
#include <hip/hip_bf16.h>
#include <math.h>

// HarmonicCausalSelfAttention: B=4 T=2048 C=1024 H=16 R=64 D=64, alpha=0.7
// R6 pipeline (4 launches):
//   k_prep : split 8 weight mats to bf16 hi/lo; fold s_r into V-mats, 0.125*log2e into qU
//   k_qkv  : FUSED x->(t)->q,k,v. Phase1: per-wave (m-half, K-half) t-partials -> LDS f32.
//            Phase2: sum + bf16 hi/lo split -> LDS (aliased). Phase3: per-wave n-quarter,
//            q,k (swapped MFMA, packed stores) + v (3-term, [B,H,D,T]).
//   k_attn : causal flash attn (unchanged from R5): uniform wave pairing, global_load_lds
//            staging w/ pre-swizzled source, XCD swizzle, exp2 softmax, defer-max
//   k_cout : FUSED y->(ty)->out. Same 3-phase structure; 2-term then 3-term; f32 out.

#define NB 4
#define NT 2048
#define NC 1024
#define NH 16
#define NR 64
#define ND 64
#define NM (NB * NT)  // 8192

typedef __attribute__((ext_vector_type(8))) short short8;
typedef __attribute__((ext_vector_type(4))) short short4v;
typedef __attribute__((ext_vector_type(4))) float f32x4;
typedef __attribute__((ext_vector_type(4))) float float4v;
typedef __attribute__((ext_vector_type(4))) int int4v;

__device__ __forceinline__ short f2bf(float f) {
    union { __hip_bfloat16 h; short s; } u;
    u.h = __float2bfloat16(f);
    return u.s;
}
__device__ __forceinline__ float bf2f(short s) {
    union { short s; __hip_bfloat16 h; } u;
    u.s = s;
    return __bfloat162float(u.h);
}
__device__ __forceinline__ f32x4 MFMA(short8 a, short8 b, f32x4 c) {
    return __builtin_amdgcn_mfma_f32_16x16x32_bf16(a, b, c, 0, 0, 0);
}
__device__ __forceinline__ float exp2_(float x) {
#if __has_builtin(__builtin_amdgcn_exp2f)
    return __builtin_amdgcn_exp2f(x);
#else
    return exp2f(x);
#endif
}
__device__ __forceinline__ void ld8_split(const float* __restrict__ p, short8& hi, short8& lo) {
    float4v a = *(const float4v*)p;
    float4v b = *(const float4v*)(p + 4);
    float v[8] = {a[0], a[1], a[2], a[3], b[0], b[1], b[2], b[3]};
#pragma unroll
    for (int j = 0; j < 8; j++) {
        short h = f2bf(v[j]);
        hi[j] = h;
        lo[j] = f2bf(v[j] - bf2f(h));
    }
}

// async global->LDS, 16B per lane (LDS dest = wave-uniform base + lane*16)
typedef const __attribute__((address_space(1))) unsigned int* gas_ptr;
typedef __attribute__((address_space(3))) unsigned int* las_ptr;
__device__ __forceinline__ void gll16(const void* g, void* l) {
    __builtin_amdgcn_global_load_lds((gas_ptr)g, (las_ptr)l, 16, 0, 0);
}

// ---- weight prep: mats 0-3 = qV,kV,vV,cV ([64][1024], scaled by s_row);
//      mats 4-7 = qU,kU,vU,cU ([1024][64]; qU additionally x 0.125*log2e)
__global__ __launch_bounds__(256) void k_prep(const float* __restrict__ qV, const float* __restrict__ kV,
                                              const float* __restrict__ vV, const float* __restrict__ cV,
                                              const float* __restrict__ qU, const float* __restrict__ kU,
                                              const float* __restrict__ vU, const float* __restrict__ cU,
                                              short* __restrict__ Whi, short* __restrict__ Wlo) {
    const int mat = blockIdx.y;
    const int idx = blockIdx.x * 256 + threadIdx.x;
    const float* src;
    switch (mat) {
        case 0: src = qV; break;
        case 1: src = kV; break;
        case 2: src = vV; break;
        case 3: src = cV; break;
        case 4: src = qU; break;
        case 5: src = kU; break;
        case 6: src = vU; break;
        default: src = cU; break;
    }
    float sc = 1.0f;
    if (mat < 4) sc = powf((float)((idx >> 10) + 1), -0.7f);
    if (mat == 4) sc = 0.125f * 1.44269504088896f;  // fold scale and log2(e)
    const float v = src[idx] * sc;
    const short h = f2bf(v);
    Whi[mat * 65536 + idx] = h;
    Wlo[mat * 65536 + idx] = f2bf(v - bf2f(h));
}

// ---- fused q/k/v: 256 blocks x 32 m-rows, 4 waves.
// Phase1: wave (ms=w&1, kc=w>>1) -> t-partial[kc][ms*16..+16][192] over K-half 512.
// Phase2: sum partials, hi/lo split -> Thi[32][200], Tlov[32][72] (LDS, aliased).
// Phase3: wave w -> n-quarter n0=w*256; q,k swapped-MFMA packed stores; v 3-term.
__global__ __launch_bounds__(256) void k_qkv(const float* __restrict__ X,
                                             const short* __restrict__ Whi, const short* __restrict__ Wlo,
                                             short* __restrict__ qb, short* __restrict__ kb,
                                             short* __restrict__ vtb) {
    __shared__ __align__(16) char smem[2 * 32 * 196 * 4];  // 50176 B
    float* Pacc = (float*)smem;                            // [2][32][196] f32
    short* Thi = (short*)smem;                             // [32][200] bf16 (aliased)
    short* Tlov = (short*)(smem + 12800);                  // [32][72] bf16
    const int tid = threadIdx.x;
    const int w = tid >> 6, l = tid & 63;
    const int lr = l & 15, lk = l >> 4;
    const int ms = w & 1, kc = w >> 1;
    const int mb = blockIdx.x * 32;
    const size_t m = (size_t)mb + ms * 16 + lr;

    const short* qVh = Whi;
    const short* kVh = Whi + 65536;
    const short* vVh = Whi + 2 * 65536;
    const short* vVl = Wlo + 2 * 65536;
    const short* qUh = Whi + 4 * 65536;
    const short* kUh = Whi + 5 * 65536;
    const short* vUh = Whi + 6 * 65536;
    const short* vUl = Wlo + 6 * 65536;

    // ---- phase 1: t-partials over this wave's K-half
    f32x4 acc[12];
#pragma unroll
    for (int j = 0; j < 12; j++) acc[j] = 0.0f;
    const int kbeg = kc * 512;
    for (int k0 = kbeg; k0 < kbeg + 512; k0 += 32) {
        short8 xh, xl;
        ld8_split(X + m * NC + k0 + lk * 8, xh, xl);
        const int bo = k0 + lk * 8;
#pragma unroll
        for (int nt = 0; nt < 4; nt++) {
            const short8 bq = *(const short8*)(qVh + (size_t)(nt * 16 + lr) * NC + bo);
            acc[nt] = MFMA(xh, bq, acc[nt]);
        }
#pragma unroll
        for (int nt = 0; nt < 4; nt++) {
            const short8 bk = *(const short8*)(kVh + (size_t)(nt * 16 + lr) * NC + bo);
            acc[4 + nt] = MFMA(xh, bk, acc[4 + nt]);
        }
#pragma unroll
        for (int nt = 0; nt < 4; nt++) {
            const short8 bvh = *(const short8*)(vVh + (size_t)(nt * 16 + lr) * NC + bo);
            const short8 bvl = *(const short8*)(vVl + (size_t)(nt * 16 + lr) * NC + bo);
            acc[8 + nt] = MFMA(xh, bvh, acc[8 + nt]);
            acc[8 + nt] = MFMA(xh, bvl, acc[8 + nt]);
            acc[8 + nt] = MFMA(xl, bvh, acc[8 + nt]);
        }
    }
    {
        float* Pw = Pacc + kc * (32 * 196);
#pragma unroll
        for (int p = 0; p < 3; p++) {
#pragma unroll
            for (int nt = 0; nt < 4; nt++) {
                const int col = p * 64 + nt * 16 + lr;
#pragma unroll
                for (int i = 0; i < 4; i++)
                    Pw[(ms * 16 + lk * 4 + i) * 196 + col] = acc[p * 4 + nt][i];
            }
        }
    }
    __syncthreads();
    // ---- phase 2: sum the 2 K-partials (6 float4 per thread), then rewrite as bf16
    float4v sums[6];
#pragma unroll
    for (int j = 0; j < 6; j++) {
        const int f = tid + 256 * j;
        const int row = f / 48, c4 = f % 48;
        const float4v a = *(const float4v*)(Pacc + row * 196 + c4 * 4);
        const float4v b = *(const float4v*)(Pacc + 32 * 196 + row * 196 + c4 * 4);
        sums[j] = a + b;
    }
    __syncthreads();
#pragma unroll
    for (int j = 0; j < 6; j++) {
        const int f = tid + 256 * j;
        const int row = f / 48, c4 = f % 48;
        short4v hi, lo;
#pragma unroll
        for (int i = 0; i < 4; i++) {
            const short h = f2bf(sums[j][i]);
            hi[i] = h;
            lo[i] = f2bf(sums[j][i] - bf2f(h));
        }
        *(short4v*)(Thi + row * 200 + c4 * 4) = hi;
        if (c4 >= 32) *(short4v*)(Tlov + row * 72 + (c4 - 32) * 4) = lo;
    }
    __syncthreads();
    // ---- phase 3: this wave's n-quarter
    const int n0 = w * 256;
    short8 tf[2][3][2];  // [ms2][path][ks] hi
    short8 tfl[2][2];    // [ms2][ks] v-lo
#pragma unroll
    for (int ms2 = 0; ms2 < 2; ms2++) {
        const int trow = ms2 * 16 + lr;
#pragma unroll
        for (int ks = 0; ks < 2; ks++) {
#pragma unroll
            for (int p = 0; p < 3; p++)
                tf[ms2][p][ks] = *(const short8*)(Thi + trow * 200 + p * 64 + ks * 32 + lk * 8);
            tfl[ms2][ks] = *(const short8*)(Tlov + trow * 72 + ks * 32 + lk * 8);
        }
    }
    const int bb = mb >> 11, mt = mb & (NT - 1);
    for (int nt = 0; nt < 16; nt++) {
        const int n = n0 + nt * 16 + lr;
        const size_t ub = (size_t)n * NR;
        short8 uq[2], uk[2], uvh[2], uvl[2];
#pragma unroll
        for (int ks = 0; ks < 2; ks++) {
            const size_t uo = ub + ks * 32 + lk * 8;
            uq[ks] = *(const short8*)(qUh + uo);
            uk[ks] = *(const short8*)(kUh + uo);
            uvh[ks] = *(const short8*)(vUh + uo);
            uvl[ks] = *(const short8*)(vUl + uo);
        }
#pragma unroll
        for (int ms2 = 0; ms2 < 2; ms2++) {
            f32x4 aq = 0.0f, ak = 0.0f, av = 0.0f;
#pragma unroll
            for (int ks = 0; ks < 2; ks++) {
                aq = MFMA(uq[ks], tf[ms2][0][ks], aq);  // swapped: lane->m, reg->n
                ak = MFMA(uk[ks], tf[ms2][1][ks], ak);
                av = MFMA(tf[ms2][2][ks], uvh[ks], av);  // unswapped: lane->n, reg->m
                av = MFMA(tf[ms2][2][ks], uvl[ks], av);
                av = MFMA(tfl[ms2][ks], uvh[ks], av);
            }
            // q,k: [B,H,T,D], lane row tt, regs run along dd -> packed 8B
            const int tt = mt + ms2 * 16 + lr;
            const int nq = n0 + nt * 16 + lk * 4;
            const int hhq = nq >> 6, ddq = nq & 63;
            short4v pq, pk;
#pragma unroll
            for (int i = 0; i < 4; i++) { pq[i] = f2bf(aq[i]); pk[i] = f2bf(ak[i]); }
            *(short4v*)(qb + ((size_t)(bb * NH + hhq) * NT + tt) * ND + ddq) = pq;
            *(short4v*)(kb + ((size_t)(bb * NH + hhq) * NT + tt) * ND + ddq) = pk;
            // v: [B,H,D,T], lane col n -> (hh,dd), regs run along tt -> packed 8B
            const int hhv = n >> 6, ddv = n & 63;
            const int tv = mt + ms2 * 16 + lk * 4;
            short4v pv;
#pragma unroll
            for (int i = 0; i < 4; i++) pv[i] = f2bf(av[i]);
            *(short4v*)(vtb + ((size_t)(bb * NH + hhv) * ND + ddv) * NT + tv) = pv;
        }
    }
}

// ---- fused c-path: y -> ty -> out. Same 3-phase structure.
__global__ __launch_bounds__(256) void k_cout(const short* __restrict__ Yb,
                                              const short* __restrict__ Whi, const short* __restrict__ Wlo,
                                              float* __restrict__ Out) {
    __shared__ __align__(16) char smem[2 * 32 * 68 * 4];  // 17408 B
    float* Pacc = (float*)smem;                           // [2][32][68] f32
    short* tyhi = (short*)smem;                           // [32][72] bf16 (aliased)
    short* tylo = (short*)(smem + 4608);                  // [32][72] bf16
    const int tid = threadIdx.x;
    const int w = tid >> 6, l = tid & 63;
    const int lr = l & 15, lk = l >> 4;
    const int ms = w & 1, kc = w >> 1;
    const int mb = blockIdx.x * 32;
    const size_t m = (size_t)mb + ms * 16 + lr;
    const short* cVh = Whi + 3 * 65536;
    const short* cVl = Wlo + 3 * 65536;
    const short* cUh = Whi + 7 * 65536;
    const short* cUl = Wlo + 7 * 65536;

    // phase 1: ty partial (2-term), K-half 512
    f32x4 acc[4];
#pragma unroll
    for (int nt = 0; nt < 4; nt++) acc[nt] = 0.0f;
    const int kbeg = kc * 512;
    for (int k0 = kbeg; k0 < kbeg + 512; k0 += 32) {
        const short8 ah = *(const short8*)(Yb + m * NC + k0 + lk * 8);
        const int bo = k0 + lk * 8;
#pragma unroll
        for (int nt = 0; nt < 4; nt++) {
            const short8 bh = *(const short8*)(cVh + (size_t)(nt * 16 + lr) * NC + bo);
            const short8 bl = *(const short8*)(cVl + (size_t)(nt * 16 + lr) * NC + bo);
            acc[nt] = MFMA(ah, bh, acc[nt]);
            acc[nt] = MFMA(ah, bl, acc[nt]);
        }
    }
    {
        float* Pw = Pacc + kc * (32 * 68);
#pragma unroll
        for (int nt = 0; nt < 4; nt++) {
#pragma unroll
            for (int i = 0; i < 4; i++)
                Pw[(ms * 16 + lk * 4 + i) * 68 + nt * 16 + lr] = acc[nt][i];
        }
    }
    __syncthreads();
    // phase 2: sum + hi/lo split (2 float4 per thread)
    float4v sums[2];
#pragma unroll
    for (int j = 0; j < 2; j++) {
        const int f = tid + 256 * j;
        const int row = f / 16, c4 = f % 16;
        const float4v a = *(const float4v*)(Pacc + row * 68 + c4 * 4);
        const float4v b = *(const float4v*)(Pacc + 32 * 68 + row * 68 + c4 * 4);
        sums[j] = a + b;
    }
    __syncthreads();
#pragma unroll
    for (int j = 0; j < 2; j++) {
        const int f = tid + 256 * j;
        const int row = f / 16, c4 = f % 16;
        short4v hi, lo;
#pragma unroll
        for (int i = 0; i < 4; i++) {
            const short h = f2bf(sums[j][i]);
            hi[i] = h;
            lo[i] = f2bf(sums[j][i] - bf2f(h));
        }
        *(short4v*)(tyhi + row * 72 + c4 * 4) = hi;
        *(short4v*)(tylo + row * 72 + c4 * 4) = lo;
    }
    __syncthreads();
    // phase 3: out = ty @ cU^T (3-term), swapped MFMA -> float4 stores
    const int n0 = w * 256;
    short8 th[2][2], tl[2][2];
#pragma unroll
    for (int ms2 = 0; ms2 < 2; ms2++) {
        const int trow = ms2 * 16 + lr;
#pragma unroll
        for (int ks = 0; ks < 2; ks++) {
            th[ms2][ks] = *(const short8*)(tyhi + trow * 72 + ks * 32 + lk * 8);
            tl[ms2][ks] = *(const short8*)(tylo + trow * 72 + ks * 32 + lk * 8);
        }
    }
    for (int nt = 0; nt < 16; nt++) {
        const size_t ub = (size_t)(n0 + nt * 16 + lr) * NR;
        short8 uh[2], ul[2];
#pragma unroll
        for (int ks = 0; ks < 2; ks++) {
            uh[ks] = *(const short8*)(cUh + ub + ks * 32 + lk * 8);
            ul[ks] = *(const short8*)(cUl + ub + ks * 32 + lk * 8);
        }
#pragma unroll
        for (int ms2 = 0; ms2 < 2; ms2++) {
            f32x4 a = 0.0f;
#pragma unroll
            for (int ks = 0; ks < 2; ks++) {
                a = MFMA(uh[ks], th[ms2][ks], a);
                a = MFMA(ul[ks], th[ms2][ks], a);
                a = MFMA(uh[ks], tl[ms2][ks], a);
            }
            const int mm = mb + ms2 * 16 + lr;
            const int n = n0 + nt * 16 + lk * 4;
            *(float4v*)(Out + (size_t)mm * NC + n) = *(float4v*)&a;
        }
    }
}

// swizzled LDS fragment read: tile [64][64] bf16, row stride 128B, byte ^ (row&7)<<4
__device__ __forceinline__ short8 lds_frag(const short* base, int row, int cb) {
    return *(const short8*)((const char*)base + (((row << 7) + cb) ^ ((row & 7) << 4)));
}

// ---- causal flash attention. grid (16, B*H) XCD-swizzled; 4 waves/block.
// Block j covers q rows [64j,64j+64) (A) and [2048-64(j+1), 2048-64j) (B);
// wave w owns 16 rows of EACH -> uniform 33 computes per wave.
// Q,K: [B,H,T,D] bf16 (Q pre-scaled by 0.125*log2e). Vt: [B,H,D,T] bf16. Y: [B,T,C] bf16.
__global__ __launch_bounds__(256, 4) void k_attn(const short* __restrict__ Qm,
                                                 const short* __restrict__ Km,
                                                 const short* __restrict__ Vt,
                                                 short* __restrict__ Y) {
    __shared__ __align__(16) short Kl[2][64 * 64];  // 16 KB dbuf, swizzled layout
    __shared__ __align__(16) short Vl[2][64 * 64];  // 16 KB
    __shared__ __align__(16) short Pl[4 * 1024];    // per-wave 16x64 P tile, swizzled
    const int tid = threadIdx.x;
    const int w = tid >> 6, l = tid & 63;
    const int lr = l & 15, lk = l >> 4;
    // bijective XCD-chunk swizzle: each XCD gets 8 complete bh's (K/V L2-resident)
    const int lin = blockIdx.y * 16 + blockIdx.x;
    const int nl = (lin & 7) * 128 + (lin >> 3);
    const int j = nl & 15;
    const int bh = nl >> 4;
    const int ntile = 32 - j;
    const int qA = 64 * j + w * 16;
    const int qB = (NT - 64 * (j + 1)) + w * 16;
    const int qrel = w * 16 + lr;  // diag-tile mask threshold (same for A and B)

    const short* Kb = Km + (size_t)bh * NT * ND;
    const short* Vb = Vt + (size_t)bh * ND * NT;

    short8 qfA[2], qfB[2];
#pragma unroll
    for (int ks = 0; ks < 2; ks++) {
        qfA[ks] = *(const short8*)(Qm + ((size_t)bh * NT + qA + lr) * ND + ks * 32 + lk * 8);
        qfB[ks] = *(const short8*)(Qm + ((size_t)bh * NT + qB + lr) * ND + ks * 32 + lk * 8);
    }

    // global_load_lds staging: LDS dest linear (wave base + lane*16); global src
    // pre-swizzled so swizzled reads see the right data (inverse of read XOR).
    const int grow8 = w * 8 + (l >> 3);                   // row within 32-row chunk
    const int gcolb = (((l & 7) ^ ((l >> 3) & 7)) << 4);  // byte col within row
    auto stage = [&](int buf, int kv0) {
        const char* kp = (const char*)Kb + (((size_t)(kv0 + grow8)) << 7) + gcolb;
        const char* vp = (const char*)Vb + (size_t)grow8 * (NT * 2) + kv0 * 2 + gcolb;
        char* kl = (char*)Kl[buf] + w * 1024;
        char* vl = (char*)Vl[buf] + w * 1024;
        gll16(kp, kl);
        gll16(kp + (32 << 7), kl + 4096);
        gll16(vp, vl);
        gll16(vp + (size_t)32 * NT * 2, vl + 4096);
    };

    float m_sA = -1e30f, l_sA = 0.0f, m_sB = -1e30f, l_sB = 0.0f;
    f32x4 oA[4], oB[4];
#pragma unroll
    for (int dt = 0; dt < 4; dt++) { oA[dt] = 0.0f; oB[dt] = 0.0f; }

    char* plb = (char*)Pl + w * 2048;

    auto compute = [&](const short8* qf, float& m_s, float& l_s, f32x4* o,
                       const short* KlB, const short* VlB, bool diag) {
        f32x4 sa[4];
#pragma unroll
        for (int nt = 0; nt < 4; nt++) sa[nt] = 0.0f;
        __builtin_amdgcn_s_setprio(1);
#pragma unroll
        for (int ks = 0; ks < 2; ks++) {
#pragma unroll
            for (int nt = 0; nt < 4; nt++) {
                const short8 kf = lds_frag(KlB, nt * 16 + lr, ks * 64 + lk * 16);
                sa[nt] = MFMA(kf, qf[ks], sa[nt]);
            }
        }
        __builtin_amdgcn_s_setprio(0);
        float sv[4][4];
        if (diag) {
#pragma unroll
            for (int nt = 0; nt < 4; nt++) {
                const int kvb = nt * 16 + lk * 4;
#pragma unroll
                for (int i = 0; i < 4; i++)
                    sv[nt][i] = (kvb + i <= qrel) ? sa[nt][i] : -1e30f;
            }
        } else {
#pragma unroll
            for (int nt = 0; nt < 4; nt++) {
#pragma unroll
                for (int i = 0; i < 4; i++) sv[nt][i] = sa[nt][i];
            }
        }
        float tmx[4];
#pragma unroll
        for (int nt = 0; nt < 4; nt++)
            tmx[nt] = fmaxf(fmaxf(fmaxf(sv[nt][0], sv[nt][1]), sv[nt][2]), sv[nt][3]);
        float pmax = fmaxf(fmaxf(fmaxf(tmx[0], tmx[1]), tmx[2]), tmx[3]);
        pmax = fmaxf(pmax, __shfl_xor(pmax, 16));
        pmax = fmaxf(pmax, __shfl_xor(pmax, 32));
        if (!__all(pmax - m_s <= 8.0f)) {  // defer-max (log2 domain)
            const float mn = fmaxf(m_s, pmax);
            const float fc = exp2_(m_s - mn);
            m_s = mn;
            l_s *= fc;
#pragma unroll
            for (int dt = 0; dt < 4; dt++) o[dt] *= fc;
        }
        float psn[4];
#pragma unroll
        for (int nt = 0; nt < 4; nt++) {
#pragma unroll
            for (int i = 0; i < 4; i++) sv[nt][i] = exp2_(sv[nt][i] - m_s);
            psn[nt] = (sv[nt][0] + sv[nt][1]) + (sv[nt][2] + sv[nt][3]);
        }
        float ps = (psn[0] + psn[1]) + (psn[2] + psn[3]);
        ps += __shfl_xor(ps, 16);
        ps += __shfl_xor(ps, 32);
        l_s += ps;
        // P^T -> per-wave LDS (b64 writes), then B-frag reads (b128)
#pragma unroll
        for (int nt = 0; nt < 4; nt++) {
            short4v pk;
#pragma unroll
            for (int i = 0; i < 4; i++) pk[i] = f2bf(sv[nt][i]);
            *(short4v*)(plb + (((lr << 7) + ((nt * 16 + lk * 4) << 1)) ^ ((lr & 7) << 4))) = pk;
        }
        const short8 pb0 = *(const short8*)(plb + (((lr << 7) + ((lk * 8) << 1)) ^ ((lr & 7) << 4)));
        const short8 pb1 = *(const short8*)(plb + (((lr << 7) + ((32 + lk * 8) << 1)) ^ ((lr & 7) << 4)));
        __builtin_amdgcn_s_setprio(1);
#pragma unroll
        for (int ks = 0; ks < 2; ks++) {
            const short8 pb = ks ? pb1 : pb0;
#pragma unroll
            for (int dt = 0; dt < 4; dt++) {
                const short8 vf = lds_frag(VlB, dt * 16 + lr, ks * 64 + lk * 16);
                o[dt] = MFMA(vf, pb, o[dt]);
            }
        }
        __builtin_amdgcn_s_setprio(0);
    };

    stage(0, 0);  // tile 0 -> buf 0
    for (int it = 0; it < ntile; ++it) {
        const int buf = it & 1;
        __syncthreads();  // drains this tile's global_load_lds (vmcnt) + syncs
        if (it + 1 < ntile) stage(buf ^ 1, (it + 1) * 64);  // overlaps compute below
        const short* KlB = Kl[buf];
        const short* VlB = Vl[buf];
        if (it <= j) compute(qfA, m_sA, l_sA, oA, KlB, VlB, it == j);
        compute(qfB, m_sB, l_sB, oB, KlB, VlB, it == ntile - 1);
    }

    const int b = bh >> 4, h = bh & 15;
    const float invA = 1.0f / l_sA, invB = 1.0f / l_sB;
    short* ypA = Y + ((size_t)b * NT + (qA + lr)) * NC + h * ND;
    short* ypB = Y + ((size_t)b * NT + (qB + lr)) * NC + h * ND;
#pragma unroll
    for (int dt = 0; dt < 4; dt++) {
        short4v ya, yb2;
#pragma unroll
        for (int i = 0; i < 4; i++) {
            ya[i] = f2bf(oA[dt][i] * invA);
            yb2[i] = f2bf(oB[dt][i] * invB);
        }
        *(short4v*)(ypA + dt * 16 + lk * 4) = ya;
        *(short4v*)(ypB + dt * 16 + lk * 4) = yb2;
    }
}

extern "C" void kernel_launch(void* const* d_in, const int* in_sizes, int n_in,
                              void* d_out, int out_size, void* d_ws, size_t ws_size,
                              hipStream_t stream) {
    const float* x = (const float*)d_in[0];
    const float* qU = (const float*)d_in[1];
    const float* qV = (const float*)d_in[2];
    const float* kU = (const float*)d_in[3];
    const float* kV = (const float*)d_in[4];
    const float* vU = (const float*)d_in[5];
    const float* vV = (const float*)d_in[6];
    const float* cU = (const float*)d_in[7];
    const float* cV = (const float*)d_in[8];
    float* out = (float*)d_out;

    char* ws = (char*)d_ws;
    size_t off = 0;
    auto take = [&](size_t bytes) {
        char* p = ws + off;
        off += (bytes + 255) & ~(size_t)255;
        return p;
    };
    short* Whi = (short*)take(8 * 65536 * 2);
    short* Wlo = (short*)take(8 * 65536 * 2);
    short* qb = (short*)take((size_t)NM * NC * 2);
    short* kb = (short*)take((size_t)NM * NC * 2);
    short* vtb = (short*)take((size_t)NM * NC * 2);
    short* yb = (short*)take((size_t)NM * NC * 2);

    k_prep<<<dim3(256, 8), 256, 0, stream>>>(qV, kV, vV, cV, qU, kU, vU, cU, Whi, Wlo);
    k_qkv<<<256, 256, 0, stream>>>(x, Whi, Wlo, qb, kb, vtb);
    k_attn<<<dim3(16, NB * NH), 256, 0, stream>>>(qb, kb, vtb, yb);
    k_cout<<<256, 256, 0, stream>>>(yb, Whi, Wlo, out);
}

// Round 8
// 165.998 us; speedup vs baseline: 4.1236x; 1.0266x over previous
//
#include <hip/hip_runtime.h>
#include <hip/hip_bf16.h>
#include <math.h>

// HarmonicCausalSelfAttention: B=4 T=2048 C=1024 H=16 R=64 D=64, alpha=0.7
// R7 pipeline (4 launches):
//   k_prep : split 8 weight mats to bf16 hi/lo; fold s_r into V-mats, 0.125*log2e into qU
//   k_qkv  : FUSED x->(t)->q,k,v. 512 blocks x 16 rows, 4 waves (K-quarter each).
//   k_attn : causal flash attn; FIXED-SHIFT softmax (M=16 baked into MFMA C-init,
//            no max tracking -- logits provably tiny; softmax is shift-invariant),
//            per-lane l-partials reduced once at end. Staging/pairing/XCD as R5/R6.
//   k_cout : FUSED y->(ty)->out. 512 blocks x 16 rows.

#define NB 4
#define NT 2048
#define NC 1024
#define NH 16
#define NR 64
#define ND 64
#define NM (NB * NT)  // 8192

typedef __attribute__((ext_vector_type(8))) short short8;
typedef __attribute__((ext_vector_type(4))) short short4v;
typedef __attribute__((ext_vector_type(4))) float f32x4;
typedef __attribute__((ext_vector_type(4))) float float4v;
typedef __attribute__((ext_vector_type(4))) int int4v;

__device__ __forceinline__ short f2bf(float f) {
    union { __hip_bfloat16 h; short s; } u;
    u.h = __float2bfloat16(f);
    return u.s;
}
__device__ __forceinline__ float bf2f(short s) {
    union { short s; __hip_bfloat16 h; } u;
    u.s = s;
    return __bfloat162float(u.h);
}
__device__ __forceinline__ f32x4 MFMA(short8 a, short8 b, f32x4 c) {
    return __builtin_amdgcn_mfma_f32_16x16x32_bf16(a, b, c, 0, 0, 0);
}
__device__ __forceinline__ float exp2_(float x) {
#if __has_builtin(__builtin_amdgcn_exp2f)
    return __builtin_amdgcn_exp2f(x);
#else
    return exp2f(x);
#endif
}
__device__ __forceinline__ void ld8_split(const float* __restrict__ p, short8& hi, short8& lo) {
    float4v a = *(const float4v*)p;
    float4v b = *(const float4v*)(p + 4);
    float v[8] = {a[0], a[1], a[2], a[3], b[0], b[1], b[2], b[3]};
#pragma unroll
    for (int j = 0; j < 8; j++) {
        short h = f2bf(v[j]);
        hi[j] = h;
        lo[j] = f2bf(v[j] - bf2f(h));
    }
}

// async global->LDS, 16B per lane (LDS dest = wave-uniform base + lane*16)
typedef const __attribute__((address_space(1))) unsigned int* gas_ptr;
typedef __attribute__((address_space(3))) unsigned int* las_ptr;
__device__ __forceinline__ void gll16(const void* g, void* l) {
    __builtin_amdgcn_global_load_lds((gas_ptr)g, (las_ptr)l, 16, 0, 0);
}

// ---- weight prep: mats 0-3 = qV,kV,vV,cV ([64][1024], scaled by s_row);
//      mats 4-7 = qU,kU,vU,cU ([1024][64]; qU additionally x 0.125*log2e)
__global__ __launch_bounds__(256) void k_prep(const float* __restrict__ qV, const float* __restrict__ kV,
                                              const float* __restrict__ vV, const float* __restrict__ cV,
                                              const float* __restrict__ qU, const float* __restrict__ kU,
                                              const float* __restrict__ vU, const float* __restrict__ cU,
                                              short* __restrict__ Whi, short* __restrict__ Wlo) {
    const int mat = blockIdx.y;
    const int idx = blockIdx.x * 256 + threadIdx.x;
    const float* src;
    switch (mat) {
        case 0: src = qV; break;
        case 1: src = kV; break;
        case 2: src = vV; break;
        case 3: src = cV; break;
        case 4: src = qU; break;
        case 5: src = kU; break;
        case 6: src = vU; break;
        default: src = cU; break;
    }
    float sc = 1.0f;
    if (mat < 4) sc = powf((float)((idx >> 10) + 1), -0.7f);
    if (mat == 4) sc = 0.125f * 1.44269504088896f;  // fold scale and log2(e)
    const float v = src[idx] * sc;
    const short h = f2bf(v);
    Whi[mat * 65536 + idx] = h;
    Wlo[mat * 65536 + idx] = f2bf(v - bf2f(h));
}

// ---- fused q/k/v: 512 blocks x 16 m-rows, 4 waves (wave = K-quarter in phase1).
// Phase1: wave kc -> t-partial[kc][16][192] over K-quarter 256 -> LDS f32.
// Phase2: sum 4 partials, hi/lo split -> Thi[16][200], Tlov[16][72] (LDS, aliased).
// Phase3: wave w -> n-quarter n0=w*256; q,k swapped-MFMA packed stores; v 3-term.
__global__ __launch_bounds__(256) void k_qkv(const float* __restrict__ X,
                                             const short* __restrict__ Whi, const short* __restrict__ Wlo,
                                             short* __restrict__ qb, short* __restrict__ kb,
                                             short* __restrict__ vtb) {
    __shared__ __align__(16) char smem[4 * 16 * 196 * 4];  // 50176 B
    float* Pacc = (float*)smem;                            // [4][16][196] f32
    short* Thi = (short*)smem;                             // [16][200] bf16 (aliased)
    short* Tlov = (short*)(smem + 6400);                   // [16][72] bf16
    const int tid = threadIdx.x;
    const int w = tid >> 6, l = tid & 63;
    const int lr = l & 15, lk = l >> 4;
    const int mb = blockIdx.x * 16;
    const size_t m = (size_t)mb + lr;

    const short* qVh = Whi;
    const short* kVh = Whi + 65536;
    const short* vVh = Whi + 2 * 65536;
    const short* vVl = Wlo + 2 * 65536;
    const short* qUh = Whi + 4 * 65536;
    const short* kUh = Whi + 5 * 65536;
    const short* vUh = Whi + 6 * 65536;
    const short* vUl = Wlo + 6 * 65536;

    // ---- phase 1: t-partials over this wave's K-quarter
    f32x4 acc[12];
#pragma unroll
    for (int j = 0; j < 12; j++) acc[j] = 0.0f;
    const int kbeg = w * 256;
    for (int k0 = kbeg; k0 < kbeg + 256; k0 += 32) {
        short8 xh, xl;
        ld8_split(X + m * NC + k0 + lk * 8, xh, xl);
        const int bo = k0 + lk * 8;
#pragma unroll
        for (int nt = 0; nt < 4; nt++) {
            const short8 bq = *(const short8*)(qVh + (size_t)(nt * 16 + lr) * NC + bo);
            acc[nt] = MFMA(xh, bq, acc[nt]);
        }
#pragma unroll
        for (int nt = 0; nt < 4; nt++) {
            const short8 bk = *(const short8*)(kVh + (size_t)(nt * 16 + lr) * NC + bo);
            acc[4 + nt] = MFMA(xh, bk, acc[4 + nt]);
        }
#pragma unroll
        for (int nt = 0; nt < 4; nt++) {
            const short8 bvh = *(const short8*)(vVh + (size_t)(nt * 16 + lr) * NC + bo);
            const short8 bvl = *(const short8*)(vVl + (size_t)(nt * 16 + lr) * NC + bo);
            acc[8 + nt] = MFMA(xh, bvh, acc[8 + nt]);
            acc[8 + nt] = MFMA(xh, bvl, acc[8 + nt]);
            acc[8 + nt] = MFMA(xl, bvh, acc[8 + nt]);
        }
    }
    {
        float* Pw = Pacc + w * (16 * 196);
#pragma unroll
        for (int p = 0; p < 3; p++) {
#pragma unroll
            for (int nt = 0; nt < 4; nt++) {
                const int col = p * 64 + nt * 16 + lr;
#pragma unroll
                for (int i = 0; i < 4; i++)
                    Pw[(lk * 4 + i) * 196 + col] = acc[p * 4 + nt][i];
            }
        }
    }
    __syncthreads();
    // ---- phase 2: sum 4 K-partials (3 float4 per thread), then rewrite as bf16
    float4v sums[3];
#pragma unroll
    for (int j = 0; j < 3; j++) {
        const int f = tid + 256 * j;
        const int row = f / 48, c4 = f % 48;
        float4v s = *(const float4v*)(Pacc + row * 196 + c4 * 4);
#pragma unroll
        for (int sIdx = 1; sIdx < 4; sIdx++)
            s += *(const float4v*)(Pacc + sIdx * (16 * 196) + row * 196 + c4 * 4);
        sums[j] = s;
    }
    __syncthreads();
#pragma unroll
    for (int j = 0; j < 3; j++) {
        const int f = tid + 256 * j;
        const int row = f / 48, c4 = f % 48;
        short4v hi, lo;
#pragma unroll
        for (int i = 0; i < 4; i++) {
            const short h = f2bf(sums[j][i]);
            hi[i] = h;
            lo[i] = f2bf(sums[j][i] - bf2f(h));
        }
        *(short4v*)(Thi + row * 200 + c4 * 4) = hi;
        if (c4 >= 32) *(short4v*)(Tlov + row * 72 + (c4 - 32) * 4) = lo;
    }
    __syncthreads();
    // ---- phase 3: this wave's n-quarter
    const int n0 = w * 256;
    short8 tf[3][2];  // [path][ks] hi
    short8 tfl[2];    // [ks] v-lo
#pragma unroll
    for (int ks = 0; ks < 2; ks++) {
#pragma unroll
        for (int p = 0; p < 3; p++)
            tf[p][ks] = *(const short8*)(Thi + lr * 200 + p * 64 + ks * 32 + lk * 8);
        tfl[ks] = *(const short8*)(Tlov + lr * 72 + ks * 32 + lk * 8);
    }
    const int bb = mb >> 11, mt = mb & (NT - 1);
    for (int nt = 0; nt < 16; nt++) {
        const int n = n0 + nt * 16 + lr;
        const size_t ub = (size_t)n * NR;
        short8 uq[2], uk[2], uvh[2], uvl[2];
#pragma unroll
        for (int ks = 0; ks < 2; ks++) {
            const size_t uo = ub + ks * 32 + lk * 8;
            uq[ks] = *(const short8*)(qUh + uo);
            uk[ks] = *(const short8*)(kUh + uo);
            uvh[ks] = *(const short8*)(vUh + uo);
            uvl[ks] = *(const short8*)(vUl + uo);
        }
        f32x4 aq = 0.0f, ak = 0.0f, av = 0.0f;
#pragma unroll
        for (int ks = 0; ks < 2; ks++) {
            aq = MFMA(uq[ks], tf[0][ks], aq);  // swapped: lane->m, reg->n
            ak = MFMA(uk[ks], tf[1][ks], ak);
            av = MFMA(tf[2][ks], uvh[ks], av);  // unswapped: lane->n, reg->m
            av = MFMA(tf[2][ks], uvl[ks], av);
            av = MFMA(tfl[ks], uvh[ks], av);
        }
        // q,k: [B,H,T,D], lane row tt, regs run along dd -> packed 8B
        const int tt = mt + lr;
        const int nq = n0 + nt * 16 + lk * 4;
        const int hhq = nq >> 6, ddq = nq & 63;
        short4v pq, pk;
#pragma unroll
        for (int i = 0; i < 4; i++) { pq[i] = f2bf(aq[i]); pk[i] = f2bf(ak[i]); }
        *(short4v*)(qb + ((size_t)(bb * NH + hhq) * NT + tt) * ND + ddq) = pq;
        *(short4v*)(kb + ((size_t)(bb * NH + hhq) * NT + tt) * ND + ddq) = pk;
        // v: [B,H,D,T], lane col n -> (hh,dd), regs run along tt -> packed 8B
        const int hhv = n >> 6, ddv = n & 63;
        const int tv = mt + lk * 4;
        short4v pv;
#pragma unroll
        for (int i = 0; i < 4; i++) pv[i] = f2bf(av[i]);
        *(short4v*)(vtb + ((size_t)(bb * NH + hhv) * ND + ddv) * NT + tv) = pv;
    }
}

// ---- fused c-path: y -> ty -> out. 512 blocks x 16 rows, same 3-phase structure.
__global__ __launch_bounds__(256) void k_cout(const short* __restrict__ Yb,
                                              const short* __restrict__ Whi, const short* __restrict__ Wlo,
                                              float* __restrict__ Out) {
    __shared__ __align__(16) char smem[4 * 16 * 68 * 4];  // 17408 B
    float* Pacc = (float*)smem;                           // [4][16][68] f32
    short* tyhi = (short*)smem;                           // [16][72] bf16 (aliased)
    short* tylo = (short*)(smem + 2304);                  // [16][72] bf16
    const int tid = threadIdx.x;
    const int w = tid >> 6, l = tid & 63;
    const int lr = l & 15, lk = l >> 4;
    const int mb = blockIdx.x * 16;
    const size_t m = (size_t)mb + lr;
    const short* cVh = Whi + 3 * 65536;
    const short* cVl = Wlo + 3 * 65536;
    const short* cUh = Whi + 7 * 65536;
    const short* cUl = Wlo + 7 * 65536;

    // phase 1: ty partial (2-term), K-quarter 256
    f32x4 acc[4];
#pragma unroll
    for (int nt = 0; nt < 4; nt++) acc[nt] = 0.0f;
    const int kbeg = w * 256;
    for (int k0 = kbeg; k0 < kbeg + 256; k0 += 32) {
        const short8 ah = *(const short8*)(Yb + m * NC + k0 + lk * 8);
        const int bo = k0 + lk * 8;
#pragma unroll
        for (int nt = 0; nt < 4; nt++) {
            const short8 bh = *(const short8*)(cVh + (size_t)(nt * 16 + lr) * NC + bo);
            const short8 bl = *(const short8*)(cVl + (size_t)(nt * 16 + lr) * NC + bo);
            acc[nt] = MFMA(ah, bh, acc[nt]);
            acc[nt] = MFMA(ah, bl, acc[nt]);
        }
    }
    {
        float* Pw = Pacc + w * (16 * 68);
#pragma unroll
        for (int nt = 0; nt < 4; nt++) {
#pragma unroll
            for (int i = 0; i < 4; i++)
                Pw[(lk * 4 + i) * 68 + nt * 16 + lr] = acc[nt][i];
        }
    }
    __syncthreads();
    // phase 2: sum + hi/lo split (1 float4 per thread)
    float4v sum;
    {
        const int row = tid / 16, c4 = tid % 16;
        sum = *(const float4v*)(Pacc + row * 68 + c4 * 4);
#pragma unroll
        for (int sIdx = 1; sIdx < 4; sIdx++)
            sum += *(const float4v*)(Pacc + sIdx * (16 * 68) + row * 68 + c4 * 4);
    }
    __syncthreads();
    {
        const int row = tid / 16, c4 = tid % 16;
        short4v hi, lo;
#pragma unroll
        for (int i = 0; i < 4; i++) {
            const short h = f2bf(sum[i]);
            hi[i] = h;
            lo[i] = f2bf(sum[i] - bf2f(h));
        }
        *(short4v*)(tyhi + row * 72 + c4 * 4) = hi;
        *(short4v*)(tylo + row * 72 + c4 * 4) = lo;
    }
    __syncthreads();
    // phase 3: out = ty @ cU^T (3-term), swapped MFMA -> float4 stores
    const int n0 = w * 256;
    short8 th[2], tl[2];
#pragma unroll
    for (int ks = 0; ks < 2; ks++) {
        th[ks] = *(const short8*)(tyhi + lr * 72 + ks * 32 + lk * 8);
        tl[ks] = *(const short8*)(tylo + lr * 72 + ks * 32 + lk * 8);
    }
    for (int nt = 0; nt < 16; nt++) {
        const size_t ub = (size_t)(n0 + nt * 16 + lr) * NR;
        short8 uh[2], ul[2];
#pragma unroll
        for (int ks = 0; ks < 2; ks++) {
            uh[ks] = *(const short8*)(cUh + ub + ks * 32 + lk * 8);
            ul[ks] = *(const short8*)(cUl + ub + ks * 32 + lk * 8);
        }
        f32x4 a = 0.0f;
#pragma unroll
        for (int ks = 0; ks < 2; ks++) {
            a = MFMA(uh[ks], th[ks], a);
            a = MFMA(ul[ks], th[ks], a);
            a = MFMA(uh[ks], tl[ks], a);
        }
        const int mm = mb + lr;
        const int n = n0 + nt * 16 + lk * 4;
        *(float4v*)(Out + (size_t)mm * NC + n) = *(float4v*)&a;
    }
}

// swizzled LDS fragment read: tile [64][64] bf16, row stride 128B, byte ^ (row&7)<<4
__device__ __forceinline__ short8 lds_frag(const short* base, int row, int cb) {
    return *(const short8*)((const char*)base + (((row << 7) + cb) ^ ((row & 7) << 4)));
}

// ---- causal flash attention. grid (16, B*H) XCD-swizzled; 4 waves/block.
// Block j covers q rows [64j,64j+64) (A) and [2048-64(j+1), 2048-64j) (B);
// wave w owns 16 rows of EACH -> uniform 33 computes per wave.
// Fixed-shift softmax: P = 2^(S-16) (shift baked into MFMA C-init; softmax is
// shift-invariant and logits are tiny, so no max tracking needed).
// Q,K: [B,H,T,D] bf16 (Q pre-scaled by 0.125*log2e). Vt: [B,H,D,T] bf16. Y: [B,T,C] bf16.
__global__ __launch_bounds__(256, 4) void k_attn(const short* __restrict__ Qm,
                                                 const short* __restrict__ Km,
                                                 const short* __restrict__ Vt,
                                                 short* __restrict__ Y) {
    __shared__ __align__(16) short Kl[2][64 * 64];  // 16 KB dbuf, swizzled layout
    __shared__ __align__(16) short Vl[2][64 * 64];  // 16 KB
    __shared__ __align__(16) short Pl[4 * 1024];    // per-wave 16x64 P tile, swizzled
    const int tid = threadIdx.x;
    const int w = tid >> 6, l = tid & 63;
    const int lr = l & 15, lk = l >> 4;
    // bijective XCD-chunk swizzle: each XCD gets 8 complete bh's (K/V L2-resident)
    const int lin = blockIdx.y * 16 + blockIdx.x;
    const int nl = (lin & 7) * 128 + (lin >> 3);
    const int j = nl & 15;
    const int bh = nl >> 4;
    const int ntile = 32 - j;
    const int qA = 64 * j + w * 16;
    const int qB = (NT - 64 * (j + 1)) + w * 16;
    const int qrel = w * 16 + lr;  // diag-tile mask threshold (same for A and B)

    const short* Kb = Km + (size_t)bh * NT * ND;
    const short* Vb = Vt + (size_t)bh * ND * NT;

    short8 qfA[2], qfB[2];
#pragma unroll
    for (int ks = 0; ks < 2; ks++) {
        qfA[ks] = *(const short8*)(Qm + ((size_t)bh * NT + qA + lr) * ND + ks * 32 + lk * 8);
        qfB[ks] = *(const short8*)(Qm + ((size_t)bh * NT + qB + lr) * ND + ks * 32 + lk * 8);
    }

    // global_load_lds staging: LDS dest linear (wave base + lane*16); global src
    // pre-swizzled so swizzled reads see the right data (inverse of read XOR).
    const int grow8 = w * 8 + (l >> 3);                   // row within 32-row chunk
    const int gcolb = (((l & 7) ^ ((l >> 3) & 7)) << 4);  // byte col within row
    auto stage = [&](int buf, int kv0) {
        const char* kp = (const char*)Kb + (((size_t)(kv0 + grow8)) << 7) + gcolb;
        const char* vp = (const char*)Vb + (size_t)grow8 * (NT * 2) + kv0 * 2 + gcolb;
        char* kl = (char*)Kl[buf] + w * 1024;
        char* vl = (char*)Vl[buf] + w * 1024;
        gll16(kp, kl);
        gll16(kp + (32 << 7), kl + 4096);
        gll16(vp, vl);
        gll16(vp + (size_t)32 * NT * 2, vl + 4096);
    };

    f32x4 lsA = 0.0f, lsB = 0.0f;  // per-lane softmax-denominator partials
    f32x4 oA[4], oB[4];
#pragma unroll
    for (int dt = 0; dt < 4; dt++) { oA[dt] = 0.0f; oB[dt] = 0.0f; }

    char* plb = (char*)Pl + w * 2048;

    auto compute = [&](const short8* qf, f32x4& ls, f32x4* o,
                       const short* KlB, const short* VlB, bool diag) {
        // S^T - 16 via C-init: lane holds S[kv=nt*16+lk*4+i][q0+lr] - 16
        f32x4 sa[4];
#pragma unroll
        for (int nt = 0; nt < 4; nt++) sa[nt] = -16.0f;
        __builtin_amdgcn_s_setprio(1);
#pragma unroll
        for (int ks = 0; ks < 2; ks++) {
#pragma unroll
            for (int nt = 0; nt < 4; nt++) {
                const short8 kf = lds_frag(KlB, nt * 16 + lr, ks * 64 + lk * 16);
                sa[nt] = MFMA(kf, qf[ks], sa[nt]);
            }
        }
        __builtin_amdgcn_s_setprio(0);
        if (diag) {
#pragma unroll
            for (int nt = 0; nt < 4; nt++) {
                const int kvb = nt * 16 + lk * 4;
#pragma unroll
                for (int i = 0; i < 4; i++)
                    if (kvb + i > qrel) sa[nt][i] = -1e30f;
            }
        }
        f32x4 sv[4];
#pragma unroll
        for (int nt = 0; nt < 4; nt++) {
#pragma unroll
            for (int i = 0; i < 4; i++) sv[nt][i] = exp2_(sa[nt][i]);
            ls += sv[nt];
        }
        // P^T -> per-wave LDS (b64 writes), then B-frag reads (b128)
#pragma unroll
        for (int nt = 0; nt < 4; nt++) {
            short4v pk;
#pragma unroll
            for (int i = 0; i < 4; i++) pk[i] = f2bf(sv[nt][i]);
            *(short4v*)(plb + (((lr << 7) + ((nt * 16 + lk * 4) << 1)) ^ ((lr & 7) << 4))) = pk;
        }
        const short8 pb0 = *(const short8*)(plb + (((lr << 7) + ((lk * 8) << 1)) ^ ((lr & 7) << 4)));
        const short8 pb1 = *(const short8*)(plb + (((lr << 7) + ((32 + lk * 8) << 1)) ^ ((lr & 7) << 4)));
        // O^T += V^T . P : lane holds O[d=dt*16+lk*4+i][q0+lr]
        __builtin_amdgcn_s_setprio(1);
#pragma unroll
        for (int ks = 0; ks < 2; ks++) {
            const short8 pb = ks ? pb1 : pb0;
#pragma unroll
            for (int dt = 0; dt < 4; dt++) {
                const short8 vf = lds_frag(VlB, dt * 16 + lr, ks * 64 + lk * 16);
                o[dt] = MFMA(vf, pb, o[dt]);
            }
        }
        __builtin_amdgcn_s_setprio(0);
    };

    stage(0, 0);  // tile 0 -> buf 0
    for (int it = 0; it < ntile; ++it) {
        const int buf = it & 1;
        __syncthreads();  // drains this tile's global_load_lds (vmcnt) + syncs
        if (it + 1 < ntile) stage(buf ^ 1, (it + 1) * 64);  // overlaps compute below
        const short* KlB = Kl[buf];
        const short* VlB = Vl[buf];
        if (it <= j) compute(qfA, lsA, oA, KlB, VlB, it == j);
        compute(qfB, lsB, oB, KlB, VlB, it == ntile - 1);
    }

    // final l reduction: row sum lives across the 4 lanes sharing lr
    float lA = (lsA[0] + lsA[1]) + (lsA[2] + lsA[3]);
    float lB = (lsB[0] + lsB[1]) + (lsB[2] + lsB[3]);
    lA += __shfl_xor(lA, 16);
    lA += __shfl_xor(lA, 32);
    lB += __shfl_xor(lB, 16);
    lB += __shfl_xor(lB, 32);

    const int b = bh >> 4, h = bh & 15;
    const float invA = 1.0f / lA, invB = 1.0f / lB;
    short* ypA = Y + ((size_t)b * NT + (qA + lr)) * NC + h * ND;
    short* ypB = Y + ((size_t)b * NT + (qB + lr)) * NC + h * ND;
#pragma unroll
    for (int dt = 0; dt < 4; dt++) {
        short4v ya, yb2;
#pragma unroll
        for (int i = 0; i < 4; i++) {
            ya[i] = f2bf(oA[dt][i] * invA);
            yb2[i] = f2bf(oB[dt][i] * invB);
        }
        *(short4v*)(ypA + dt * 16 + lk * 4) = ya;
        *(short4v*)(ypB + dt * 16 + lk * 4) = yb2;
    }
}

extern "C" void kernel_launch(void* const* d_in, const int* in_sizes, int n_in,
                              void* d_out, int out_size, void* d_ws, size_t ws_size,
                              hipStream_t stream) {
    const float* x = (const float*)d_in[0];
    const float* qU = (const float*)d_in[1];
    const float* qV = (const float*)d_in[2];
    const float* kU = (const float*)d_in[3];
    const float* kV = (const float*)d_in[4];
    const float* vU = (const float*)d_in[5];
    const float* vV = (const float*)d_in[6];
    const float* cU = (const float*)d_in[7];
    const float* cV = (const float*)d_in[8];
    float* out = (float*)d_out;

    char* ws = (char*)d_ws;
    size_t off = 0;
    auto take = [&](size_t bytes) {
        char* p = ws + off;
        off += (bytes + 255) & ~(size_t)255;
        return p;
    };
    short* Whi = (short*)take(8 * 65536 * 2);
    short* Wlo = (short*)take(8 * 65536 * 2);
    short* qb = (short*)take((size_t)NM * NC * 2);
    short* kb = (short*)take((size_t)NM * NC * 2);
    short* vtb = (short*)take((size_t)NM * NC * 2);
    short* yb = (short*)take((size_t)NM * NC * 2);

    k_prep<<<dim3(256, 8), 256, 0, stream>>>(qV, kV, vV, cV, qU, kU, vU, cU, Whi, Wlo);
    k_qkv<<<512, 256, 0, stream>>>(x, Whi, Wlo, qb, kb, vtb);
    k_attn<<<dim3(16, NB * NH), 256, 0, stream>>>(qb, kb, vtb, yb);
    k_cout<<<512, 256, 0, stream>>>(yb, Whi, Wlo, out);
}